// Round 5
// baseline (477.211 us; speedup 1.0000x reference)
//
#include <hip/hip_runtime.h>
#include <math.h>

#define B_ 8
#define T_ 1000
#define F_ 96
#define C_ 16
#define D_ 64
#define EPS_ 1e-5f
#define CH_ 40

typedef short bfrag8 __attribute__((ext_vector_type(8)));
typedef float facc4 __attribute__((ext_vector_type(4)));
typedef float f2v __attribute__((ext_vector_type(2)));
#define MFMA16 __builtin_amdgcn_mfma_f32_16x16x32_bf16

__device__ __forceinline__ float gelu_erf(float v){
    return 0.5f*v*(1.0f+erff(v*0.70710678118654752440f));
}
__device__ __forceinline__ float dot4(float4 a, float4 b){
    return a.x*b.x + a.y*b.y + a.z*b.z + a.w*b.w;
}
__device__ __forceinline__ float ex2(float x){   // 2^x, bare v_exp_f32
    float r; asm("v_exp_f32 %0, %1" : "=v"(r) : "v"(x)); return r;
}
__device__ __forceinline__ float ex2n(float x){  // 2^(-x)
    float r; asm("v_exp_f32 %0, -%1" : "=v"(r) : "v"(x)); return r;
}
__device__ __forceinline__ unsigned short f2bf(float x){
    unsigned int u = __float_as_uint(x);
    return (unsigned short)((u + 0x7fffu + ((u>>16)&1u)) >> 16);
}
__device__ __forceinline__ float bf2f(unsigned short s){
    return __uint_as_float(((unsigned int)s)<<16);
}
__device__ __forceinline__ unsigned int pack2bf(float a, float b){
    return (unsigned int)f2bf(a) | ((unsigned int)f2bf(b)<<16);
}

// ---------------- Kernel P: weight-only precompute (1 block) ----------------
__global__ __launch_bounds__(256) void k_prep(
    const float* __restrict__ wq, const float* __restrict__ bq,
    const float* __restrict__ wk, const float* __restrict__ bk,
    const float* __restrict__ wv, const float* __restrict__ wo,
    const float* __restrict__ wm1, const float* __restrict__ wm2,
    short* __restrict__ gtb, float* __restrict__ uvw,
    short* __restrict__ wv_bf, short* __restrict__ wo_bf,
    short* __restrict__ wm1_bf, short* __restrict__ wm2_bf)
{
    int tid = threadIdx.x;
    int c1 = tid & 15, c2 = tid >> 4;
    float acc = 0.f;
    #pragma unroll 8
    for (int d=0; d<64; ++d)
        acc += wq[d*16 + c1] * wk[d*16 + c2];
    gtb[c2*16 + c1] = (short)f2bf(0.125f * acc);
    if (tid < 16){
        float a = 0.f;
        for (int d=0; d<64; ++d) a += wq[d*16 + tid] * bk[d];
        uvw[tid] = 0.125f * a;
    } else if (tid < 32){
        int cc = tid - 16;
        float a = 0.f;
        for (int d=0; d<64; ++d) a += bq[d] * wk[d*16 + cc];
        uvw[16 + cc] = 0.125f * a;
    } else if (tid == 32){
        float a = 0.f;
        for (int d=0; d<64; ++d) a += bq[d] * bk[d];
        uvw[32] = 0.125f * a;
    }
    for (int i = tid; i < 1024; i += 256){
        wv_bf[i] = (short)f2bf(wv[i]);
        wo_bf[i] = (short)f2bf(wo[i]);
    }
    if (tid < 256){
        wm1_bf[tid] = (short)f2bf(wm1[tid]);
        wm2_bf[tid] = (short)f2bf(wm2[tid]);
    }
}

// ---------------- Kernel A: conv_in -> x [B,T,F,C] ----------------
__global__ __launch_bounds__(128) void k_conv_in(
    const float* __restrict__ in, const float* __restrict__ g, const float* __restrict__ bb,
    const float* __restrict__ w_in, const float* __restrict__ b_in,
    float* __restrict__ x)
{
    int bt = blockIdx.x; int b = bt / T_; int t = bt % T_;
    int tid = threadIdx.x;
    __shared__ float r0[128], r1[128], r2[128], r3[128];
    float i0=0.f, i1=0.f;
    size_t base0 = ((size_t)(b*2+0)*T_ + t)*F_;
    size_t base1 = ((size_t)(b*2+1)*T_ + t)*F_;
    if (tid < F_){ i0 = in[base0+tid]; i1 = in[base1+tid]; }
    r0[tid]=i0; r1[tid]=i0*i0; r2[tid]=i1; r3[tid]=i1*i1;
    __syncthreads();
    for (int s=64; s>0; s>>=1){
        if (tid < s){ r0[tid]+=r0[tid+s]; r1[tid]+=r1[tid+s]; r2[tid]+=r2[tid+s]; r3[tid]+=r3[tid+s]; }
        __syncthreads();
    }
    float m0 = r0[0]*(1.f/F_), m1 = r2[0]*(1.f/F_);
    float ri0 = rsqrtf(r1[0]*(1.f/F_) - m0*m0 + EPS_);
    float ri1 = rsqrtf(r3[0]*(1.f/F_) - m1*m1 + EPS_);
    if (tid < F_){
        float gg = g[tid], b0 = bb[tid];
        float y0 = (i0-m0)*ri0*gg + b0;
        float y1 = (i1-m1)*ri1*gg + b0;
        float xv[16];
        #pragma unroll
        for (int c=0;c<C_;++c){
            xv[c] = gelu_erf(w_in[c*2+0]*y0 + w_in[c*2+1]*y1 + b_in[c]);
        }
        float4* xp = (float4*)(x + (((size_t)b*T_+t)*F_ + tid)*C_);
        xp[0] = make_float4(xv[0],xv[1],xv[2],xv[3]);
        xp[1] = make_float4(xv[4],xv[5],xv[6],xv[7]);
        xp[2] = make_float4(xv[8],xv[9],xv[10],xv[11]);
        xp[3] = make_float4(xv[12],xv[13],xv[14],xv[15]);
    }
}

// ---------------- Kernel B: ConvGRU — R3 structure (unchanged) ----------------
#define DPPF(src, ctrl) __int_as_float(__builtin_amdgcn_update_dpp(0, __float_as_int(src), (ctrl), 0xF, 0xF, false))
#define L2E_ 1.44269504088896340736f

__global__ __launch_bounds__(192, 1) void k_gru(
    const float* __restrict__ x, const float* __restrict__ wx, const float* __restrict__ wh,
    float* __restrict__ hs, float* __restrict__ d_out)
{
    int blk = blockIdx.x;
    int b = blk / 24, f0 = (blk % 24) * 4;
    int tid = threadIdx.x;
    int wave = tid >> 6, lane = tid & 63;
    int c = lane & 15, ch = lane >> 4;
    int f = f0 + ch;

    __shared__ float GG[2][(CH_+1)*192];

    if (wave != 0){
        float4 Wxz[4], Wxr[4], Wxn[4];
        #pragma unroll
        for (int q=0;q<4;++q){
            float4 az = *(const float4*)(wx + ( 0+c)*16 + 4*q);
            float4 ar = *(const float4*)(wx + (16+c)*16 + 4*q);
            float4 an = *(const float4*)(wx + (32+c)*16 + 4*q);
            Wxz[q] = make_float4(az.x*L2E_, az.y*L2E_, az.z*L2E_, az.w*L2E_);
            Wxr[q] = make_float4(ar.x*L2E_, ar.y*L2E_, ar.z*L2E_, ar.w*L2E_);
            Wxn[q] = make_float4(an.x*2.f*L2E_, an.y*2.f*L2E_, an.z*2.f*L2E_, an.w*2.f*L2E_);
        }
        const float* gb0 = x + (size_t)b*T_*(F_*C_) + f*C_;
        const int tl0 = (wave-1)*(CH_/2);
        #define PRODUCE(K, BF) { \
            _Pragma("unroll 4") \
            for (int tl=tl0; tl<tl0+(CH_/2); ++tl){ \
                const float* xp2 = gb0 + (size_t)((K)*CH_ + tl)*(F_*C_); \
                float4 x0 = *(const float4*)(xp2 + 0); \
                float4 x1 = *(const float4*)(xp2 + 4); \
                float4 x2 = *(const float4*)(xp2 + 8); \
                float4 x3 = *(const float4*)(xp2 + 12); \
                float zx = dot4(Wxz[0],x0)+dot4(Wxz[1],x1)+dot4(Wxz[2],x2)+dot4(Wxz[3],x3); \
                float rx = dot4(Wxr[0],x0)+dot4(Wxr[1],x1)+dot4(Wxr[2],x2)+dot4(Wxr[3],x3); \
                float nx = dot4(Wxn[0],x0)+dot4(Wxn[1],x1)+dot4(Wxn[2],x2)+dot4(Wxn[3],x3); \
                float* gq = &GG[BF][tl*192 + lane]; \
                gq[0] = zx; gq[64] = rx; gq[128] = nx; \
            } }
        PRODUCE(0, 0);
        __syncthreads();
        for (int k=0; k<T_/CH_; ++k){
            if (k+1 < T_/CH_){
                if ((k+1)&1){ PRODUCE(k+1, 1); } else { PRODUCE(k+1, 0); }
            }
            __syncthreads();
        }
        #undef PRODUCE
    } else {
        const int pm0[8] = {0,2,7,5,15,13,8,10};
        const int pm1[8] = {1,3,6,4,14,12,9,11};
        f2v Wz[8], Wr[8], Wn[8];
        #pragma unroll
        for (int j=0;j<8;++j){
            int ka = c ^ pm0[j], kb = c ^ pm1[j];
            Wz[j].x = L2E_*wh[( 0+c)*16 + ka];      Wz[j].y = L2E_*wh[( 0+c)*16 + kb];
            Wr[j].x = L2E_*wh[(16+c)*16 + ka];      Wr[j].y = L2E_*wh[(16+c)*16 + kb];
            Wn[j].x = 2.f*L2E_*wh[(32+c)*16 + ka];  Wn[j].y = 2.f*L2E_*wh[(32+c)*16 + kb];
        }
        float hc = 0.f;
        size_t hsb = (size_t)b*T_*(F_*C_) + f0*C_ + lane;
        __syncthreads();
        for (int k=0; k<T_/CH_; ++k){
            const float* gp = GG[k&1];
            float gzv = gp[lane], grv = gp[64+lane], gnv = gp[128+lane];
            #pragma unroll 4
            for (int tl=0; tl<CH_; ++tl){
                const float* np = gp + (tl+1)*192 + lane;
                float gzn = np[0], grn = np[64], gnn = np[128];
                f2v A0, P2, P7, P5, PF, PD, P8, PA;
                A0.x = hc;              A0.y = DPPF(hc, 0xB1);
                P2.x = DPPF(A0.x,0x4E); P2.y = DPPF(A0.y,0x4E);
                P7.x = DPPF(A0.x,0x141);P7.y = DPPF(A0.y,0x141);
                P5.x = DPPF(P7.x,0x4E); P5.y = DPPF(P7.y,0x4E);
                PF.x = DPPF(A0.x,0x140);PF.y = DPPF(A0.y,0x140);
                PD.x = DPPF(PF.x,0x4E); PD.y = DPPF(PF.y,0x4E);
                P8.x = DPPF(PF.x,0x141);P8.y = DPPF(PF.y,0x141);
                PA.x = DPPF(P8.x,0x4E); PA.y = DPPF(P8.y,0x4E);
                f2v sz = Wz[0]*A0, sr = Wr[0]*A0, sn = Wn[0]*A0;
                sz = __builtin_elementwise_fma(Wz[1],P2,sz);
                sr = __builtin_elementwise_fma(Wr[1],P2,sr);
                sn = __builtin_elementwise_fma(Wn[1],P2,sn);
                sz = __builtin_elementwise_fma(Wz[2],P7,sz);
                sr = __builtin_elementwise_fma(Wr[2],P7,sr);
                sn = __builtin_elementwise_fma(Wn[2],P7,sn);
                sz = __builtin_elementwise_fma(Wz[3],P5,sz);
                sr = __builtin_elementwise_fma(Wr[3],P5,sr);
                sn = __builtin_elementwise_fma(Wn[3],P5,sn);
                sz = __builtin_elementwise_fma(Wz[4],PF,sz);
                sr = __builtin_elementwise_fma(Wr[4],PF,sr);
                sn = __builtin_elementwise_fma(Wn[4],PF,sn);
                sz = __builtin_elementwise_fma(Wz[5],PD,sz);
                sr = __builtin_elementwise_fma(Wr[5],PD,sr);
                sn = __builtin_elementwise_fma(Wn[5],PD,sn);
                sz = __builtin_elementwise_fma(Wz[6],P8,sz);
                sr = __builtin_elementwise_fma(Wr[6],P8,sr);
                sn = __builtin_elementwise_fma(Wn[6],P8,sn);
                sz = __builtin_elementwise_fma(Wz[7],PA,sz);
                sr = __builtin_elementwise_fma(Wr[7],PA,sr);
                sn = __builtin_elementwise_fma(Wn[7],PA,sn);
                float z = __builtin_amdgcn_rcpf(1.f + ex2n((gzv + sz.x) + sz.y));
                float r = __builtin_amdgcn_rcpf(1.f + ex2n((grv + sr.x) + sr.y));
                float u = __builtin_amdgcn_rcpf(1.f + ex2(fmaf(r, sn.x + sn.y, gnv)));
                float n = fmaf(-2.f, u, 1.f);
                hc = n + z*(hc - n);
                hs[hsb + (size_t)(k*CH_ + tl)*(F_*C_)] = hc;
                gzv = gzn; grv = grn; gnv = gnn;
            }
            __syncthreads();
        }
        d_out[(size_t)B_*2*T_*F_ + ((size_t)b*C_ + c)*F_ + f] = hc;
    }
}

// ---------------- Kernel C: fused attention + MLP + conv_out (MFMA bf16) ----------------
// LDS map (float offsets; _SH = short offsets = 2x float offset). TOTF 13528 fl = 54.1 KB -> 3 blocks/CU.
#define XR_FL   0        // [96][16] fp32 residual, in place (0..1536)
#define YB_SH   3072     // [96][24]sh bf16 ynorm / ynorm2          (fl 1536..2688)
#define YGB_SH  5376     // [96][24]sh bf16 y*G / Y1                (fl 2688..3840)
#define PG_SH   3072     // [96][48]sh long probs (overlay YB+YGB, S5-S6)
#define YMB_SH  7680     // [32][24]sh segment means                (fl 3840..4224)
#define E_FL    4224     // 96
#define GL_FL   4320     // 96
#define GM_FL   4416     // 24
#define VBT_SH  8880     // [64][96]sh v^T[d][f]                    (fl 4440..7512)
#define VLBT_SH 15024    // [64][32]sh v_long^T[d][m]               (fl 7512..8536)
// ---- pool (fl 8536..13528), time-disjoint overlays:
#define SC_FL   8536     // [96][29] fp32 scores (S4-S5): loc 0..3 compact, long 4..27
#define OB_SH   17072    // [96][72]sh o[f][d] (S6-S7)              (fl 8536..11992)
#define PL_SH   23984    // [96][32]sh local probs (S5-S6)          (fl 11992..13528)
#define GTB_SH  17072    // [16][24]sh G^T (S0-S3; dead before S4)  (fl 8536..8728)
#define UU_FL   8728     // 16  (S0-S3)
#define VV_FL   8744     // 16  (S0-S3)
#define W0_FL   8760     // 1   (S0-S3)
#define OSC_FL  8776     // 512 LN scratch (transient: S1b/S8/S9)
#define MEA_FL  9288     // 16  (S1b->S2, S8, S9)
#define RST_FL  9304     // 16
#define TOTF    13528

__device__ __forceinline__ void ln_stats16(float* S, int tid){
    int c = tid & 15, g = tid >> 4;
    float s=0.f, q=0.f;
    #pragma unroll
    for (int i=0;i<6;++i){
        float v = S[XR_FL + (g*6+i)*16 + c];
        s += v; q += v*v;
    }
    S[OSC_FL + g*16 + c] = s;
    S[OSC_FL + 256 + g*16 + c] = q;
    __syncthreads();
    if (tid < 16){
        float Sm=0.f, Q=0.f;
        #pragma unroll
        for (int g2=0; g2<16; ++g2){
            Sm += S[OSC_FL + g2*16 + tid];
            Q  += S[OSC_FL + 256 + g2*16 + tid];
        }
        float m = Sm*(1.f/96.f);
        S[MEA_FL+tid] = m;
        S[RST_FL+tid] = rsqrtf(Q*(1.f/96.f) - m*m + EPS_);
    }
    __syncthreads();
}

__global__ __launch_bounds__(256) void k_tail(
    const float* __restrict__ x, const float* __restrict__ hs, const float* __restrict__ input,
    const float* __restrict__ ln_att_g, const float* __restrict__ ln_att_b,
    const short* __restrict__ gtb, const float* __restrict__ uvw,
    const short* __restrict__ wv_bf, const float* __restrict__ bv,
    const short* __restrict__ wo_bf, const float* __restrict__ bo,
    const float* __restrict__ ln_m_g, const float* __restrict__ ln_m_b,
    const short* __restrict__ wm1_bf, const float* __restrict__ bm1,
    const short* __restrict__ wm2_bf, const float* __restrict__ bm2,
    const float* __restrict__ ln_o_g, const float* __restrict__ ln_o_b,
    const float* __restrict__ w_out, const float* __restrict__ b_out,
    float* __restrict__ out)
{
    int bt = blockIdx.x; int b = bt / T_; int t = bt % T_;
    int tid = threadIdx.x;
    int w = tid >> 6, lane = tid & 63;
    int n = lane & 15, q2 = lane >> 4;
    __shared__ float S[TOTF];
    short* Ssh = (short*)S;
    const bfrag8 ZF = {0,0,0,0,0,0,0,0};

    size_t xbase = ((size_t)b*T_ + t)*(size_t)(F_*C_);

    // ---- S0: loads ----
    {
        const float4* xg = (const float4*)(x + xbase);
        const float4* hg = (const float4*)(hs + xbase);
        float4* XR4 = (float4*)(S + XR_FL);
        for (int i4 = tid; i4 < 384; i4 += 256){
            float4 a = xg[i4], h = hg[i4];
            XR4[i4] = make_float4(a.x+h.x, a.y+h.y, a.z+h.z, a.w+h.w);
        }
        if (tid < 64){
            int cc2 = tid >> 2, c1g = (tid & 3)*4;
            *(uint2*)(Ssh + GTB_SH + cc2*24 + c1g) = *(const uint2*)(gtb + cc2*16 + c1g);
        } else if (tid < 97){
            S[UU_FL + (tid - 64)] = uvw[tid - 64];   // UU(16)|VV(16)|W0(1)
        }
    }
    bfrag8 Bv = ZF, Bm1 = ZF, Bm2 = ZF;
    if (q2 < 2){
        Bv  = *(const bfrag8*)(wv_bf  + (16*w + n)*16 + q2*8);
        Bm1 = *(const bfrag8*)(wm1_bf + n*16 + q2*8);
        Bm2 = *(const bfrag8*)(wm2_bf + n*16 + q2*8);
    }
    bfrag8 Bo0 = *(const bfrag8*)(wo_bf + n*64 + q2*8);
    bfrag8 Bo1 = *(const bfrag8*)(wo_bf + n*64 + 32 + q2*8);
    float bvr  = bv[16*w + n];
    float bor  = bo[n];
    float bm1r = bm1[n];
    float bm2r = bm2[n];
    __syncthreads();

    // ---- S1b: attention LN stats ----
    ln_stats16(S, tid);

    // ---- S2: normalize -> YB ----
    {
        float4* XR4 = (float4*)(S + XR_FL);
        for (int i4 = tid; i4 < 384; i4 += 256){
            int f = i4 >> 2, c4 = i4 & 3;
            float4 v = XR4[i4];
            float4 m4 = *(float4*)(S + MEA_FL + 4*c4);
            float4 r4 = *(float4*)(S + RST_FL + 4*c4);
            float gg = ln_att_g[f], b2 = ln_att_b[f];
            float y0 = (v.x - m4.x)*r4.x*gg + b2;
            float y1 = (v.y - m4.y)*r4.y*gg + b2;
            float y2 = (v.z - m4.z)*r4.z*gg + b2;
            float y3 = (v.w - m4.w)*r4.w*gg + b2;
            uint2 pk = make_uint2(pack2bf(y0,y1), pack2bf(y2,y3));
            *(uint2*)(Ssh + YB_SH + f*24 + c4*4) = pk;
        }
    }
    __syncthreads();

    // ---- S2b: E/GL, segment means, zero YMB rows 24..31 ----
    if (tid < 96){
        int f = tid;
        float yv[16];
        uint4 u0 = *(const uint4*)(Ssh + YB_SH + f*24);
        uint4 u1 = *(const uint4*)(Ssh + YB_SH + f*24 + 8);
        unsigned int uu[8] = {u0.x,u0.y,u0.z,u0.w,u1.x,u1.y,u1.z,u1.w};
        #pragma unroll
        for (int j=0;j<8;++j){
            yv[2*j]   = bf2f((unsigned short)(uu[j] & 0xffff));
            yv[2*j+1] = bf2f((unsigned short)(uu[j] >> 16));
        }
        float de = 0.f, dg = 0.f;
        #pragma unroll
        for (int cc=0; cc<16; ++cc){
            de += yv[cc]*S[UU_FL+cc];
            dg += yv[cc]*S[VV_FL+cc];
        }
        S[E_FL + f]  = de + S[W0_FL];
        S[GL_FL + f] = dg;
    }
    for (int e = tid; e < 384; e += 256){
        int m = e >> 4, cc = e & 15;
        float sm = bf2f((unsigned short)Ssh[YB_SH + (4*m+0)*24 + cc])
                 + bf2f((unsigned short)Ssh[YB_SH + (4*m+1)*24 + cc])
                 + bf2f((unsigned short)Ssh[YB_SH + (4*m+2)*24 + cc])
                 + bf2f((unsigned short)Ssh[YB_SH + (4*m+3)*24 + cc]);
        Ssh[YMB_SH + m*24 + cc] = (short)f2bf(0.25f*sm);
    }
    if (tid < 128){
        int row = 24 + (tid >> 4), cc = tid & 15;
        Ssh[YMB_SH + row*24 + cc] = 0;
    }
    __syncthreads();

    // ---- S3: MFMA — v (VBT stride 96), v_long (VLBT stride 32), YG; GM ----
    {
        #pragma unroll
        for (int mt=0; mt<6; ++mt){
            bfrag8 A = ZF;
            if (q2 < 2) A = *(const bfrag8*)(Ssh + YB_SH + (mt*16 + n)*24 + q2*8);
            facc4 acc = {bvr, bvr, bvr, bvr};
            acc = MFMA16(A, Bv, acc, 0, 0, 0);
            uint2 pk = make_uint2(pack2bf(acc[0],acc[1]), pack2bf(acc[2],acc[3]));
            *(uint2*)(Ssh + VBT_SH + (16*w + n)*96 + mt*16 + q2*4) = pk;
        }
        #pragma unroll
        for (int mt=0; mt<2; ++mt){
            bfrag8 A = ZF;
            if (q2 < 2) A = *(const bfrag8*)(Ssh + YMB_SH + (mt*16 + n)*24 + q2*8);
            facc4 acc = {bvr, bvr, bvr, bvr};
            acc = MFMA16(A, Bv, acc, 0, 0, 0);
            uint2 pk = make_uint2(pack2bf(acc[0],acc[1]), pack2bf(acc[2],acc[3]));
            *(uint2*)(Ssh + VLBT_SH + (16*w + n)*32 + mt*16 + q2*4) = pk;
        }
        bfrag8 Bg = ZF;
        if (q2 < 2) Bg = *(const bfrag8*)(Ssh + GTB_SH + n*24 + q2*8);
        for (int mt = w; mt < 6; mt += 4){
            bfrag8 A = ZF;
            if (q2 < 2) A = *(const bfrag8*)(Ssh + YB_SH + (mt*16 + n)*24 + q2*8);
            facc4 acc = {0.f,0.f,0.f,0.f};
            acc = MFMA16(A, Bg, acc, 0, 0, 0);
            #pragma unroll
            for (int r=0;r<4;++r)
                Ssh[YGB_SH + (mt*16 + q2*4 + r)*24 + n] = (short)f2bf(acc[r]);
        }
        if (tid >= 224 && tid < 248){
            int m = tid - 224;
            float a2 = 0.f;
            #pragma unroll
            for (int cc=0; cc<16; ++cc)
                a2 += bf2f((unsigned short)Ssh[YMB_SH + m*24 + cc]) * S[VV_FL + cc];
            S[GM_FL + m] = a2;
        }
    }
    __syncthreads();

    // ---- S4: scores -> SC stride 29 (local compacted to cols 0..3; lsq == q2 on write side) ----
    for (int j = w; j < 18; j += 4){
        int mt = j / 3, kind = j % 3;
        bfrag8 A = ZF;
        if (q2 < 2) A = *(const bfrag8*)(Ssh + YGB_SH + (mt*16 + n)*24 + q2*8);
        bfrag8 Bf = ZF;
        if (kind == 0){
            if (q2 < 2) Bf = *(const bfrag8*)(Ssh + YB_SH + (mt*16 + n)*24 + q2*8);
        } else {
            int nt = kind - 1;
            if (q2 < 2) Bf = *(const bfrag8*)(Ssh + YMB_SH + (nt*16 + n)*24 + q2*8);
        }
        facc4 acc = {0.f,0.f,0.f,0.f};
        acc = MFMA16(A, Bf, acc, 0, 0, 0);
        if (kind == 0){
            if ((n >> 2) == q2){
                #pragma unroll
                for (int r=0;r<4;++r)
                    S[SC_FL + (mt*16 + q2*4 + r)*29 + (n & 3)] = acc[r];
            }
        } else {
            int nt = kind - 1;
            if (!(nt == 1 && n >= 8)){
                #pragma unroll
                for (int r=0;r<4;++r)
                    S[SC_FL + (mt*16 + q2*4 + r)*29 + 4 + nt*16 + n] = acc[r];
            }
        }
    }
    __syncthreads();

    // ---- S5: softmax (threads 0..95) ----
    if (tid < 96){
        int f = tid;
        int lsq = (f >> 2) & 3;
        float e_ = S[E_FL + f];
        const float* row = S + SC_FL + f*29;
        float sl[4];
        #pragma unroll
        for (int j=0;j<4;++j)
            sl[j] = row[j] + e_ + S[GL_FL + (f & ~3) + j];
        float sg[24];
        #pragma unroll
        for (int m=0;m<24;++m)
            sg[m] = row[4 + m] + e_ + S[GM_FL + m];
        float mx = sl[0];
        #pragma unroll
        for (int j=1;j<4;++j) mx = fmaxf(mx, sl[j]);
        #pragma unroll
        for (int m=0;m<24;++m) mx = fmaxf(mx, sg[m]);
        float sum = 0.f;
        #pragma unroll
        for (int j=0;j<4;++j){ sl[j] = __expf(sl[j]-mx); sum += sl[j]; }
        #pragma unroll
        for (int m=0;m<24;++m){ sg[m] = __expf(sg[m]-mx); sum += sg[m]; }
        float inv = __builtin_amdgcn_rcpf(sum);
        // PL row (stride 32 sh): local probs at cols 4*lsq..4*lsq+3, rest zero
        unsigned int lo = pack2bf(sl[0]*inv, sl[1]*inv);
        unsigned int hi = pack2bf(sl[2]*inv, sl[3]*inv);
        uint4 z4 = make_uint4(0u,0u,0u,0u);
        uint4 p0 = make_uint4(lsq==0?lo:0u, lsq==0?hi:0u, lsq==1?lo:0u, lsq==1?hi:0u);
        uint4 p1 = make_uint4(lsq==2?lo:0u, lsq==2?hi:0u, lsq==3?lo:0u, lsq==3?hi:0u);
        uint4* plp = (uint4*)(Ssh + PL_SH + f*32);
        plp[0] = p0; plp[1] = p1; plp[2] = z4; plp[3] = z4;
        // PG row (stride 48 sh, overlay YB/YGB): 24 bf16 + 8 zeros
        unsigned int gdw[12];
        #pragma unroll
        for (int m=0;m<12;++m) gdw[m] = pack2bf(sg[2*m]*inv, sg[2*m+1]*inv);
        uint4* pgp = (uint4*)(Ssh + PG_SH + f*48);
        pgp[0] = make_uint4(gdw[0],gdw[1],gdw[2],gdw[3]);
        pgp[1] = make_uint4(gdw[4],gdw[5],gdw[6],gdw[7]);
        pgp[2] = make_uint4(gdw[8],gdw[9],gdw[10],gdw[11]);
        pgp[3] = z4;
    }
    __syncthreads();

    // ---- S6: o^T -> OB (overlays SC region; SC dead) ----
    {
        bfrag8 Avl = *(const bfrag8*)(Ssh + VLBT_SH + (16*w + n)*32 + q2*8);
        #pragma unroll
        for (int nt=0; nt<6; ++nt){
            bfrag8 Avb = *(const bfrag8*)(Ssh + VBT_SH + (16*w + n)*96 + nt*16 + q2*8);
            bfrag8 Bpl = *(const bfrag8*)(Ssh + PL_SH + (nt*16 + n)*32 + q2*8);
            bfrag8 Bpg = *(const bfrag8*)(Ssh + PG_SH + (nt*16 + n)*48 + q2*8);
            facc4 acc = {0.f,0.f,0.f,0.f};
            acc = MFMA16(Avb, Bpl, acc, 0, 0, 0);
            acc = MFMA16(Avl, Bpg, acc, 0, 0, 0);
            uint2 pk = make_uint2(pack2bf(acc[0],acc[1]), pack2bf(acc[2],acc[3]));
            *(uint2*)(Ssh + OB_SH + (nt*16 + n)*72 + 16*w + q2*4) = pk;
        }
    }
    __syncthreads();

    // ---- S7: out-proj + residual into XR ----
    for (int mt = w; mt < 6; mt += 4){
        bfrag8 A0 = *(const bfrag8*)(Ssh + OB_SH + (mt*16 + n)*72 + 0*32 + q2*8);
        bfrag8 A1 = *(const bfrag8*)(Ssh + OB_SH + (mt*16 + n)*72 + 1*32 + q2*8);
        facc4 acc = {bor, bor, bor, bor};
        acc = MFMA16(A0, Bo0, acc, 0, 0, 0);
        acc = MFMA16(A1, Bo1, acc, 0, 0, 0);
        #pragma unroll
        for (int r=0;r<4;++r)
            S[XR_FL + (mt*16 + q2*4 + r)*16 + n] += acc[r];
    }
    __syncthreads();

    // ---- S8: MLP ----
    ln_stats16(S, tid);
    {
        float4* XR4 = (float4*)(S + XR_FL);
        for (int i4 = tid; i4 < 384; i4 += 256){
            int f = i4 >> 2, c4 = i4 & 3;
            float4 v = XR4[i4];
            float4 m4 = *(float4*)(S + MEA_FL + 4*c4);
            float4 r4 = *(float4*)(S + RST_FL + 4*c4);
            float gg = ln_m_g[f], b2 = ln_m_b[f];
            float y0 = (v.x - m4.x)*r4.x*gg + b2;
            float y1 = (v.y - m4.y)*r4.y*gg + b2;
            float y2 = (v.z - m4.z)*r4.z*gg + b2;
            float y3 = (v.w - m4.w)*r4.w*gg + b2;
            uint2 pk = make_uint2(pack2bf(y0,y1), pack2bf(y2,y3));
            *(uint2*)(Ssh + YB_SH + f*24 + c4*4) = pk;
        }
    }
    __syncthreads();
    for (int mt = w; mt < 6; mt += 4){
        bfrag8 A = ZF;
        if (q2 < 2) A = *(const bfrag8*)(Ssh + YB_SH + (mt*16 + n)*24 + q2*8);
        facc4 acc = {bm1r, bm1r, bm1r, bm1r};
        acc = MFMA16(A, Bm1, acc, 0, 0, 0);
        #pragma unroll
        for (int r=0;r<4;++r)
            Ssh[YGB_SH + (mt*16 + q2*4 + r)*24 + n] = (short)f2bf(gelu_erf(acc[r]));
    }
    __syncthreads();
    for (int mt = w; mt < 6; mt += 4){
        bfrag8 A = ZF;
        if (q2 < 2) A = *(const bfrag8*)(Ssh + YGB_SH + (mt*16 + n)*24 + q2*8);
        facc4 acc = {bm2r, bm2r, bm2r, bm2r};
        acc = MFMA16(A, Bm2, acc, 0, 0, 0);
        #pragma unroll
        for (int r=0;r<4;++r)
            S[XR_FL + (mt*16 + q2*4 + r)*16 + n] += acc[r];
    }
    __syncthreads();

    // ---- S9: conv_out + outer residual ----
    ln_stats16(S, tid);
    if (tid < 192){
        int ch = tid >= 96, f = tid - 96*ch;
        float gg = ln_o_g[f], b2 = ln_o_b[f];
        float acc = b_out[ch];
        float4* XR4 = (float4*)(S + XR_FL);
        #pragma unroll
        for (int c4=0;c4<4;++c4){
            float4 x4 = XR4[f*4 + c4];
            float4 m4 = *(float4*)(S + MEA_FL + 4*c4);
            float4 r4 = *(float4*)(S + RST_FL + 4*c4);
            float4 w4 = *(const float4*)(w_out + ch*16 + 4*c4);
            float4 tm;
            tm.x = (x4.x - m4.x)*r4.x*gg + b2;
            tm.y = (x4.y - m4.y)*r4.y*gg + b2;
            tm.z = (x4.z - m4.z)*r4.z*gg + b2;
            tm.w = (x4.w - m4.w)*r4.w*gg + b2;
            acc += dot4(w4, tm);
        }
        size_t oidx = ((size_t)(b*2+ch)*T_ + t)*F_ + f;
        out[oidx] = input[oidx] + tanhf(acc);
    }
}

extern "C" void kernel_launch(void* const* d_in, const int* in_sizes, int n_in,
                              void* d_out, int out_size, void* d_ws, size_t ws_size,
                              hipStream_t stream)
{
    const float* input   = (const float*)d_in[0];
    const float* ln_in_g = (const float*)d_in[1];
    const float* ln_in_b = (const float*)d_in[2];
    const float* w_in    = (const float*)d_in[3];
    const float* b_in    = (const float*)d_in[4];
    const float* gru_wx  = (const float*)d_in[5];
    const float* gru_wh  = (const float*)d_in[6];
    const float* ln_att_g= (const float*)d_in[7];
    const float* ln_att_b= (const float*)d_in[8];
    const float* wq = (const float*)d_in[9];
    const float* bq = (const float*)d_in[10];
    const float* wk = (const float*)d_in[11];
    const float* bk = (const float*)d_in[12];
    const float* wv = (const float*)d_in[13];
    const float* bv = (const float*)d_in[14];
    const float* wo = (const float*)d_in[15];
    const float* bo = (const float*)d_in[16];
    const float* ln_m_g = (const float*)d_in[17];
    const float* ln_m_b = (const float*)d_in[18];
    const float* w_m1 = (const float*)d_in[19];
    const float* b_m1 = (const float*)d_in[20];
    const float* w_m2 = (const float*)d_in[21];
    const float* b_m2 = (const float*)d_in[22];
    const float* ln_out_g = (const float*)d_in[23];
    const float* ln_out_b = (const float*)d_in[24];
    const float* w_out = (const float*)d_in[25];
    const float* b_out = (const float*)d_in[26];
    float* out = (float*)d_out;

    const size_t NX = (size_t)B_*T_*F_*C_;          // 12,288,000
    float* x   = (float*)d_ws;                      // [B,T,F,C]
    float* hs  = x + NX;                            // [B,T,F,C]
    float* uvw = x + 2*NX;                          // 33 floats (padded to 64)
    short* wv_bf  = (short*)(x + 2*NX + 64);        // 16B-aligned
    short* wo_bf  = wv_bf + 1024;
    short* wm1_bf = wo_bf + 1024;
    short* wm2_bf = wm1_bf + 256;
    short* gtb    = wm2_bf + 256;

    k_prep<<<1, 256, 0, stream>>>(wq, bq, wk, bk, wv, wo, w_m1, w_m2,
                                  gtb, uvw, wv_bf, wo_bf, wm1_bf, wm2_bf);
    k_conv_in<<<B_*T_, 128, 0, stream>>>(input, ln_in_g, ln_in_b, w_in, b_in, x);
    k_gru<<<192, 192, 0, stream>>>(x, gru_wx, gru_wh, hs, out);
    k_tail<<<B_*T_, 256, 0, stream>>>(x, hs, input, ln_att_g, ln_att_b,
        gtb, uvw, wv_bf, bv, wo_bf, bo, ln_m_g, ln_m_b, wm1_bf, b_m1, wm2_bf, b_m2,
        ln_out_g, ln_out_b, w_out, b_out, out);
}

// Round 6
// 426.386 us; speedup vs baseline: 1.1192x; 1.1192x over previous
//
#include <hip/hip_runtime.h>
#include <math.h>

#define B_ 8
#define T_ 1000
#define F_ 96
#define C_ 16
#define D_ 64
#define EPS_ 1e-5f
#define CH_ 40

typedef short bfrag8 __attribute__((ext_vector_type(8)));
typedef float facc4 __attribute__((ext_vector_type(4)));
typedef float f2v __attribute__((ext_vector_type(2)));
#define MFMA16 __builtin_amdgcn_mfma_f32_16x16x32_bf16

__device__ __forceinline__ float gelu_erf(float v){
    return 0.5f*v*(1.0f+erff(v*0.70710678118654752440f));
}
__device__ __forceinline__ float dot4(float4 a, float4 b){
    return a.x*b.x + a.y*b.y + a.z*b.z + a.w*b.w;
}
__device__ __forceinline__ float ex2(float x){   // 2^x, bare v_exp_f32
    float r; asm("v_exp_f32 %0, %1" : "=v"(r) : "v"(x)); return r;
}
__device__ __forceinline__ float ex2n(float x){  // 2^(-x)
    float r; asm("v_exp_f32 %0, -%1" : "=v"(r) : "v"(x)); return r;
}
__device__ __forceinline__ unsigned short f2bf(float x){
    unsigned int u = __float_as_uint(x);
    return (unsigned short)((u + 0x7fffu + ((u>>16)&1u)) >> 16);
}
__device__ __forceinline__ float bf2f(unsigned short s){
    return __uint_as_float(((unsigned int)s)<<16);
}
__device__ __forceinline__ unsigned int pack2bf(float a, float b){
    return (unsigned int)f2bf(a) | ((unsigned int)f2bf(b)<<16);
}

// ---------------- Kernel P: weight-only precompute (1 block) ----------------
__global__ __launch_bounds__(256) void k_prep(
    const float* __restrict__ wq, const float* __restrict__ bq,
    const float* __restrict__ wk, const float* __restrict__ bk,
    const float* __restrict__ wv, const float* __restrict__ wo,
    const float* __restrict__ wm1, const float* __restrict__ wm2,
    short* __restrict__ gtb, float* __restrict__ uvw,
    short* __restrict__ wv_bf, short* __restrict__ wo_bf,
    short* __restrict__ wm1_bf, short* __restrict__ wm2_bf)
{
    int tid = threadIdx.x;
    int c1 = tid & 15, c2 = tid >> 4;
    float acc = 0.f;
    #pragma unroll 8
    for (int d=0; d<64; ++d)
        acc += wq[d*16 + c1] * wk[d*16 + c2];
    gtb[c2*16 + c1] = (short)f2bf(0.125f * acc);
    if (tid < 16){
        float a = 0.f;
        for (int d=0; d<64; ++d) a += wq[d*16 + tid] * bk[d];
        uvw[tid] = 0.125f * a;
    } else if (tid < 32){
        int cc = tid - 16;
        float a = 0.f;
        for (int d=0; d<64; ++d) a += bq[d] * wk[d*16 + cc];
        uvw[16 + cc] = 0.125f * a;
    } else if (tid == 32){
        float a = 0.f;
        for (int d=0; d<64; ++d) a += bq[d] * bk[d];
        uvw[32] = 0.125f * a;
    }
    for (int i = tid; i < 1024; i += 256){
        wv_bf[i] = (short)f2bf(wv[i]);
        wo_bf[i] = (short)f2bf(wo[i]);
    }
    if (tid < 256){
        wm1_bf[tid] = (short)f2bf(wm1[tid]);
        wm2_bf[tid] = (short)f2bf(wm2[tid]);
    }
}

// ---------------- Kernel A: conv_in -> x [B,T,F,C] ----------------
__global__ __launch_bounds__(128) void k_conv_in(
    const float* __restrict__ in, const float* __restrict__ g, const float* __restrict__ bb,
    const float* __restrict__ w_in, const float* __restrict__ b_in,
    float* __restrict__ x)
{
    int bt = blockIdx.x; int b = bt / T_; int t = bt % T_;
    int tid = threadIdx.x;
    __shared__ float r0[128], r1[128], r2[128], r3[128];
    float i0=0.f, i1=0.f;
    size_t base0 = ((size_t)(b*2+0)*T_ + t)*F_;
    size_t base1 = ((size_t)(b*2+1)*T_ + t)*F_;
    if (tid < F_){ i0 = in[base0+tid]; i1 = in[base1+tid]; }
    r0[tid]=i0; r1[tid]=i0*i0; r2[tid]=i1; r3[tid]=i1*i1;
    __syncthreads();
    for (int s=64; s>0; s>>=1){
        if (tid < s){ r0[tid]+=r0[tid+s]; r1[tid]+=r1[tid+s]; r2[tid]+=r2[tid+s]; r3[tid]+=r3[tid+s]; }
        __syncthreads();
    }
    float m0 = r0[0]*(1.f/F_), m1 = r2[0]*(1.f/F_);
    float ri0 = rsqrtf(r1[0]*(1.f/F_) - m0*m0 + EPS_);
    float ri1 = rsqrtf(r3[0]*(1.f/F_) - m1*m1 + EPS_);
    if (tid < F_){
        float gg = g[tid], b0 = bb[tid];
        float y0 = (i0-m0)*ri0*gg + b0;
        float y1 = (i1-m1)*ri1*gg + b0;
        float xv[16];
        #pragma unroll
        for (int c=0;c<C_;++c){
            xv[c] = gelu_erf(w_in[c*2+0]*y0 + w_in[c*2+1]*y1 + b_in[c]);
        }
        float4* xp = (float4*)(x + (((size_t)b*T_+t)*F_ + tid)*C_);
        xp[0] = make_float4(xv[0],xv[1],xv[2],xv[3]);
        xp[1] = make_float4(xv[4],xv[5],xv[6],xv[7]);
        xp[2] = make_float4(xv[8],xv[9],xv[10],xv[11]);
        xp[3] = make_float4(xv[12],xv[13],xv[14],xv[15]);
    }
}

// ---------------- Kernel B: ConvGRU — R3 structure (unchanged) ----------------
#define DPPF(src, ctrl) __int_as_float(__builtin_amdgcn_update_dpp(0, __float_as_int(src), (ctrl), 0xF, 0xF, false))
#define L2E_ 1.44269504088896340736f

__global__ __launch_bounds__(192, 1) void k_gru(
    const float* __restrict__ x, const float* __restrict__ wx, const float* __restrict__ wh,
    float* __restrict__ hs, float* __restrict__ d_out)
{
    int blk = blockIdx.x;
    int b = blk / 24, f0 = (blk % 24) * 4;
    int tid = threadIdx.x;
    int wave = tid >> 6, lane = tid & 63;
    int c = lane & 15, ch = lane >> 4;
    int f = f0 + ch;

    __shared__ float GG[2][(CH_+1)*192];

    if (wave != 0){
        float4 Wxz[4], Wxr[4], Wxn[4];
        #pragma unroll
        for (int q=0;q<4;++q){
            float4 az = *(const float4*)(wx + ( 0+c)*16 + 4*q);
            float4 ar = *(const float4*)(wx + (16+c)*16 + 4*q);
            float4 an = *(const float4*)(wx + (32+c)*16 + 4*q);
            Wxz[q] = make_float4(az.x*L2E_, az.y*L2E_, az.z*L2E_, az.w*L2E_);
            Wxr[q] = make_float4(ar.x*L2E_, ar.y*L2E_, ar.z*L2E_, ar.w*L2E_);
            Wxn[q] = make_float4(an.x*2.f*L2E_, an.y*2.f*L2E_, an.z*2.f*L2E_, an.w*2.f*L2E_);
        }
        const float* gb0 = x + (size_t)b*T_*(F_*C_) + f*C_;
        const int tl0 = (wave-1)*(CH_/2);
        #define PRODUCE(K, BF) { \
            _Pragma("unroll 4") \
            for (int tl=tl0; tl<tl0+(CH_/2); ++tl){ \
                const float* xp2 = gb0 + (size_t)((K)*CH_ + tl)*(F_*C_); \
                float4 x0 = *(const float4*)(xp2 + 0); \
                float4 x1 = *(const float4*)(xp2 + 4); \
                float4 x2 = *(const float4*)(xp2 + 8); \
                float4 x3 = *(const float4*)(xp2 + 12); \
                float zx = dot4(Wxz[0],x0)+dot4(Wxz[1],x1)+dot4(Wxz[2],x2)+dot4(Wxz[3],x3); \
                float rx = dot4(Wxr[0],x0)+dot4(Wxr[1],x1)+dot4(Wxr[2],x2)+dot4(Wxr[3],x3); \
                float nx = dot4(Wxn[0],x0)+dot4(Wxn[1],x1)+dot4(Wxn[2],x2)+dot4(Wxn[3],x3); \
                float* gq = &GG[BF][tl*192 + lane]; \
                gq[0] = zx; gq[64] = rx; gq[128] = nx; \
            } }
        PRODUCE(0, 0);
        __syncthreads();
        for (int k=0; k<T_/CH_; ++k){
            if (k+1 < T_/CH_){
                if ((k+1)&1){ PRODUCE(k+1, 1); } else { PRODUCE(k+1, 0); }
            }
            __syncthreads();
        }
        #undef PRODUCE
    } else {
        const int pm0[8] = {0,2,7,5,15,13,8,10};
        const int pm1[8] = {1,3,6,4,14,12,9,11};
        f2v Wz[8], Wr[8], Wn[8];
        #pragma unroll
        for (int j=0;j<8;++j){
            int ka = c ^ pm0[j], kb = c ^ pm1[j];
            Wz[j].x = L2E_*wh[( 0+c)*16 + ka];      Wz[j].y = L2E_*wh[( 0+c)*16 + kb];
            Wr[j].x = L2E_*wh[(16+c)*16 + ka];      Wr[j].y = L2E_*wh[(16+c)*16 + kb];
            Wn[j].x = 2.f*L2E_*wh[(32+c)*16 + ka];  Wn[j].y = 2.f*L2E_*wh[(32+c)*16 + kb];
        }
        float hc = 0.f;
        size_t hsb = (size_t)b*T_*(F_*C_) + f0*C_ + lane;
        __syncthreads();
        for (int k=0; k<T_/CH_; ++k){
            const float* gp = GG[k&1];
            float gzv = gp[lane], grv = gp[64+lane], gnv = gp[128+lane];
            #pragma unroll 4
            for (int tl=0; tl<CH_; ++tl){
                const float* np = gp + (tl+1)*192 + lane;
                float gzn = np[0], grn = np[64], gnn = np[128];
                f2v A0, P2, P7, P5, PF, PD, P8, PA;
                A0.x = hc;              A0.y = DPPF(hc, 0xB1);
                P2.x = DPPF(A0.x,0x4E); P2.y = DPPF(A0.y,0x4E);
                P7.x = DPPF(A0.x,0x141);P7.y = DPPF(A0.y,0x141);
                P5.x = DPPF(P7.x,0x4E); P5.y = DPPF(P7.y,0x4E);
                PF.x = DPPF(A0.x,0x140);PF.y = DPPF(A0.y,0x140);
                PD.x = DPPF(PF.x,0x4E); PD.y = DPPF(PF.y,0x4E);
                P8.x = DPPF(PF.x,0x141);P8.y = DPPF(PF.y,0x141);
                PA.x = DPPF(P8.x,0x4E); PA.y = DPPF(P8.y,0x4E);
                f2v sz = Wz[0]*A0, sr = Wr[0]*A0, sn = Wn[0]*A0;
                sz = __builtin_elementwise_fma(Wz[1],P2,sz);
                sr = __builtin_elementwise_fma(Wr[1],P2,sr);
                sn = __builtin_elementwise_fma(Wn[1],P2,sn);
                sz = __builtin_elementwise_fma(Wz[2],P7,sz);
                sr = __builtin_elementwise_fma(Wr[2],P7,sr);
                sn = __builtin_elementwise_fma(Wn[2],P7,sn);
                sz = __builtin_elementwise_fma(Wz[3],P5,sz);
                sr = __builtin_elementwise_fma(Wr[3],P5,sr);
                sn = __builtin_elementwise_fma(Wn[3],P5,sn);
                sz = __builtin_elementwise_fma(Wz[4],PF,sz);
                sr = __builtin_elementwise_fma(Wr[4],PF,sr);
                sn = __builtin_elementwise_fma(Wn[4],PF,sn);
                sz = __builtin_elementwise_fma(Wz[5],PD,sz);
                sr = __builtin_elementwise_fma(Wr[5],PD,sr);
                sn = __builtin_elementwise_fma(Wn[5],PD,sn);
                sz = __builtin_elementwise_fma(Wz[6],P8,sz);
                sr = __builtin_elementwise_fma(Wr[6],P8,sr);
                sn = __builtin_elementwise_fma(Wn[6],P8,sn);
                sz = __builtin_elementwise_fma(Wz[7],PA,sz);
                sr = __builtin_elementwise_fma(Wr[7],PA,sr);
                sn = __builtin_elementwise_fma(Wn[7],PA,sn);
                float z = __builtin_amdgcn_rcpf(1.f + ex2n((gzv + sz.x) + sz.y));
                float r = __builtin_amdgcn_rcpf(1.f + ex2n((grv + sr.x) + sr.y));
                float u = __builtin_amdgcn_rcpf(1.f + ex2(fmaf(r, sn.x + sn.y, gnv)));
                float n = fmaf(-2.f, u, 1.f);
                hc = n + z*(hc - n);
                hs[hsb + (size_t)(k*CH_ + tl)*(F_*C_)] = hc;
                gzv = gzn; grv = grn; gnv = gnn;
            }
            __syncthreads();
        }
        d_out[(size_t)B_*2*T_*F_ + ((size_t)b*C_ + c)*F_ + f] = hc;
    }
}

// ---------------- Kernel C: fused attention + MLP + conv_out (MFMA bf16) ----------------
// LDS map (float offsets; _SH = short = 2x). TOTF 13144 fl = 52.6 KB -> 3 blocks/CU target.
// Swizzles (16B granules): OB g^=row&7 ; VBT/VLBT/PL g^=(row>>1)&3.
#define XR_FL   0        // [96][16] fp32 residual, in place (0..1536)
#define YB_SH   3072     // [96][24]sh bf16 ynorm / ynorm2          (fl 1536..2688)
#define YGB_SH  5376     // [96][24]sh bf16 y*G / Y1                (fl 2688..3840)
#define PG_SH   3072     // [96][48]sh long probs (overlay YB+YGB, S5-S6)
#define YMB_SH  7680     // [32][24]sh segment means                (fl 3840..4224)
#define E_FL    4224     // 96
#define GL_FL   4320     // 96
#define GM_FL   4416     // 24
#define VBT_SH  8880     // [64][96]sh v^T[d][f], swizzled          (fl 4440..7512)
#define VLBT_SH 15024    // [64][32]sh v_long^T[d][m], swizzled     (fl 7512..8536)
// ---- pool (fl 8536..13144), time-disjoint overlays:
#define SC_FL   8536     // [96][29] fp32 scores (S4-S5)
#define OB_SH   17072    // [96][64]sh o[f][d], swizzled (S6-S7)    (fl 8536..11608)
#define PL_SH   23216    // [96][32]sh local probs, swizzled (S5-S6)(fl 11608..13144)
#define GTB_SH  17072    // [16][24]sh G^T (S0-S3)                  (fl 8536..8728)
#define UU_FL   8728     // 16  (S0-S3)
#define VV_FL   8744     // 16  (S0-S3)
#define W0_FL   8760     // 1   (S0-S3)
#define OSC_FL  8776     // 512 LN scratch (S1b/S8/S9)
#define MEA_FL  9288     // 16
#define RST_FL  9304     // 16
#define TOTF    13144

__device__ __forceinline__ void ln_stats16(float* S, int tid){
    int c = tid & 15, g = tid >> 4;
    float s=0.f, q=0.f;
    #pragma unroll
    for (int i=0;i<6;++i){
        float v = S[XR_FL + (g*6+i)*16 + c];
        s += v; q += v*v;
    }
    S[OSC_FL + g*16 + c] = s;
    S[OSC_FL + 256 + g*16 + c] = q;
    __syncthreads();
    if (tid < 16){
        float Sm=0.f, Q=0.f;
        #pragma unroll
        for (int g2=0; g2<16; ++g2){
            Sm += S[OSC_FL + g2*16 + tid];
            Q  += S[OSC_FL + 256 + g2*16 + tid];
        }
        float m = Sm*(1.f/96.f);
        S[MEA_FL+tid] = m;
        S[RST_FL+tid] = rsqrtf(Q*(1.f/96.f) - m*m + EPS_);
    }
    __syncthreads();
}

__global__ __launch_bounds__(256) void k_tail(
    const float* __restrict__ x, const float* __restrict__ hs, const float* __restrict__ input,
    const float* __restrict__ ln_att_g, const float* __restrict__ ln_att_b,
    const short* __restrict__ gtb, const float* __restrict__ uvw,
    const short* __restrict__ wv_bf, const float* __restrict__ bv,
    const short* __restrict__ wo_bf, const float* __restrict__ bo,
    const float* __restrict__ ln_m_g, const float* __restrict__ ln_m_b,
    const short* __restrict__ wm1_bf, const float* __restrict__ bm1,
    const short* __restrict__ wm2_bf, const float* __restrict__ bm2,
    const float* __restrict__ ln_o_g, const float* __restrict__ ln_o_b,
    const float* __restrict__ w_out, const float* __restrict__ b_out,
    float* __restrict__ out)
{
    int bt = blockIdx.x; int b = bt / T_; int t = bt % T_;
    int tid = threadIdx.x;
    int w = tid >> 6, lane = tid & 63;
    int n = lane & 15, q2 = lane >> 4;
    __shared__ float S[TOTF];
    short* Ssh = (short*)S;
    const bfrag8 ZF = {0,0,0,0,0,0,0,0};
    const int svl = (n >> 1) & 3;   // swizzle key for VBT/VLBT/PL
    const int swo = n & 7;          // swizzle key for OB

    size_t xbase = ((size_t)b*T_ + t)*(size_t)(F_*C_);

    // ---- S0: loads ----
    {
        const float4* xg = (const float4*)(x + xbase);
        const float4* hg = (const float4*)(hs + xbase);
        float4* XR4 = (float4*)(S + XR_FL);
        for (int i4 = tid; i4 < 384; i4 += 256){
            float4 a = xg[i4], h = hg[i4];
            XR4[i4] = make_float4(a.x+h.x, a.y+h.y, a.z+h.z, a.w+h.w);
        }
        if (tid < 64){
            int cc2 = tid >> 2, c1g = (tid & 3)*4;
            *(uint2*)(Ssh + GTB_SH + cc2*24 + c1g) = *(const uint2*)(gtb + cc2*16 + c1g);
        } else if (tid < 97){
            S[UU_FL + (tid - 64)] = uvw[tid - 64];   // UU(16)|VV(16)|W0(1)
        }
    }
    bfrag8 Bv = ZF, Bm1 = ZF, Bm2 = ZF;
    if (q2 < 2){
        Bv  = *(const bfrag8*)(wv_bf  + (16*w + n)*16 + q2*8);
        Bm1 = *(const bfrag8*)(wm1_bf + n*16 + q2*8);
        Bm2 = *(const bfrag8*)(wm2_bf + n*16 + q2*8);
    }
    bfrag8 Bo0 = *(const bfrag8*)(wo_bf + n*64 + q2*8);
    bfrag8 Bo1 = *(const bfrag8*)(wo_bf + n*64 + 32 + q2*8);
    float bvr  = bv[16*w + n];
    float bor  = bo[n];
    float bm1r = bm1[n];
    float bm2r = bm2[n];
    __syncthreads();

    // ---- S1b: attention LN stats ----
    ln_stats16(S, tid);

    // ---- S2: normalize -> YB ----
    {
        float4* XR4 = (float4*)(S + XR_FL);
        for (int i4 = tid; i4 < 384; i4 += 256){
            int f = i4 >> 2, c4 = i4 & 3;
            float4 v = XR4[i4];
            float4 m4 = *(float4*)(S + MEA_FL + 4*c4);
            float4 r4 = *(float4*)(S + RST_FL + 4*c4);
            float gg = ln_att_g[f], b2 = ln_att_b[f];
            float y0 = (v.x - m4.x)*r4.x*gg + b2;
            float y1 = (v.y - m4.y)*r4.y*gg + b2;
            float y2 = (v.z - m4.z)*r4.z*gg + b2;
            float y3 = (v.w - m4.w)*r4.w*gg + b2;
            uint2 pk = make_uint2(pack2bf(y0,y1), pack2bf(y2,y3));
            *(uint2*)(Ssh + YB_SH + f*24 + c4*4) = pk;
        }
    }
    __syncthreads();

    // ---- S2b: E/GL, segment means, zero YMB rows 24..31 ----
    if (tid < 96){
        int f = tid;
        float yv[16];
        uint4 u0 = *(const uint4*)(Ssh + YB_SH + f*24);
        uint4 u1 = *(const uint4*)(Ssh + YB_SH + f*24 + 8);
        unsigned int uu[8] = {u0.x,u0.y,u0.z,u0.w,u1.x,u1.y,u1.z,u1.w};
        #pragma unroll
        for (int j=0;j<8;++j){
            yv[2*j]   = bf2f((unsigned short)(uu[j] & 0xffff));
            yv[2*j+1] = bf2f((unsigned short)(uu[j] >> 16));
        }
        float de = 0.f, dg = 0.f;
        #pragma unroll
        for (int cc=0; cc<16; ++cc){
            de += yv[cc]*S[UU_FL+cc];
            dg += yv[cc]*S[VV_FL+cc];
        }
        S[E_FL + f]  = de + S[W0_FL];
        S[GL_FL + f] = dg;
    }
    for (int e = tid; e < 384; e += 256){
        int m = e >> 4, cc = e & 15;
        float sm = bf2f((unsigned short)Ssh[YB_SH + (4*m+0)*24 + cc])
                 + bf2f((unsigned short)Ssh[YB_SH + (4*m+1)*24 + cc])
                 + bf2f((unsigned short)Ssh[YB_SH + (4*m+2)*24 + cc])
                 + bf2f((unsigned short)Ssh[YB_SH + (4*m+3)*24 + cc]);
        Ssh[YMB_SH + m*24 + cc] = (short)f2bf(0.25f*sm);
    }
    if (tid < 128){
        int row = 24 + (tid >> 4), cc = tid & 15;
        Ssh[YMB_SH + row*24 + cc] = 0;
    }
    __syncthreads();

    // ---- S3: MFMA — v (VBT sw), v_long (VLBT sw), YG; GM ----
    {
        #pragma unroll
        for (int mt=0; mt<6; ++mt){
            bfrag8 A = ZF;
            if (q2 < 2) A = *(const bfrag8*)(Ssh + YB_SH + (mt*16 + n)*24 + q2*8);
            facc4 acc = {bvr, bvr, bvr, bvr};
            acc = MFMA16(A, Bv, acc, 0, 0, 0);
            uint2 pk = make_uint2(pack2bf(acc[0],acc[1]), pack2bf(acc[2],acc[3]));
            int g = 2*mt + (q2>>1);
            *(uint2*)(Ssh + VBT_SH + (16*w + n)*96 + ((g^svl)<<3) + ((q2&1)<<2)) = pk;
        }
        #pragma unroll
        for (int mt=0; mt<2; ++mt){
            bfrag8 A = ZF;
            if (q2 < 2) A = *(const bfrag8*)(Ssh + YMB_SH + (mt*16 + n)*24 + q2*8);
            facc4 acc = {bvr, bvr, bvr, bvr};
            acc = MFMA16(A, Bv, acc, 0, 0, 0);
            uint2 pk = make_uint2(pack2bf(acc[0],acc[1]), pack2bf(acc[2],acc[3]));
            int g = 2*mt + (q2>>1);
            *(uint2*)(Ssh + VLBT_SH + (16*w + n)*32 + ((g^svl)<<3) + ((q2&1)<<2)) = pk;
        }
        bfrag8 Bg = ZF;
        if (q2 < 2) Bg = *(const bfrag8*)(Ssh + GTB_SH + n*24 + q2*8);
        for (int mt = w; mt < 6; mt += 4){
            bfrag8 A = ZF;
            if (q2 < 2) A = *(const bfrag8*)(Ssh + YB_SH + (mt*16 + n)*24 + q2*8);
            facc4 acc = {0.f,0.f,0.f,0.f};
            acc = MFMA16(A, Bg, acc, 0, 0, 0);
            #pragma unroll
            for (int r=0;r<4;++r)
                Ssh[YGB_SH + (mt*16 + q2*4 + r)*24 + n] = (short)f2bf(acc[r]);
        }
        if (tid >= 224 && tid < 248){
            int m = tid - 224;
            float a2 = 0.f;
            #pragma unroll
            for (int cc=0; cc<16; ++cc)
                a2 += bf2f((unsigned short)Ssh[YMB_SH + m*24 + cc]) * S[VV_FL + cc];
            S[GM_FL + m] = a2;
        }
    }
    __syncthreads();

    // ---- S4: scores -> SC stride 29 (local compacted to cols 0..3) ----
    for (int j = w; j < 18; j += 4){
        int mt = j / 3, kind = j % 3;
        bfrag8 A = ZF;
        if (q2 < 2) A = *(const bfrag8*)(Ssh + YGB_SH + (mt*16 + n)*24 + q2*8);
        bfrag8 Bf = ZF;
        if (kind == 0){
            if (q2 < 2) Bf = *(const bfrag8*)(Ssh + YB_SH + (mt*16 + n)*24 + q2*8);
        } else {
            int nt = kind - 1;
            if (q2 < 2) Bf = *(const bfrag8*)(Ssh + YMB_SH + (nt*16 + n)*24 + q2*8);
        }
        facc4 acc = {0.f,0.f,0.f,0.f};
        acc = MFMA16(A, Bf, acc, 0, 0, 0);
        if (kind == 0){
            if ((n >> 2) == q2){
                #pragma unroll
                for (int r=0;r<4;++r)
                    S[SC_FL + (mt*16 + q2*4 + r)*29 + (n & 3)] = acc[r];
            }
        } else {
            int nt = kind - 1;
            if (!(nt == 1 && n >= 8)){
                #pragma unroll
                for (int r=0;r<4;++r)
                    S[SC_FL + (mt*16 + q2*4 + r)*29 + 4 + nt*16 + n] = acc[r];
            }
        }
    }
    __syncthreads();

    // ---- S5: softmax (threads 0..95) ----
    if (tid < 96){
        int f = tid;
        int lsq = (f >> 2) & 3;
        float e_ = S[E_FL + f];
        const float* row = S + SC_FL + f*29;
        float sl[4];
        #pragma unroll
        for (int j=0;j<4;++j)
            sl[j] = row[j] + e_ + S[GL_FL + (f & ~3) + j];
        float sg[24];
        #pragma unroll
        for (int m=0;m<24;++m)
            sg[m] = row[4 + m] + e_ + S[GM_FL + m];
        float mx = sl[0];
        #pragma unroll
        for (int j=1;j<4;++j) mx = fmaxf(mx, sl[j]);
        #pragma unroll
        for (int m=0;m<24;++m) mx = fmaxf(mx, sg[m]);
        float sum = 0.f;
        #pragma unroll
        for (int j=0;j<4;++j){ sl[j] = __expf(sl[j]-mx); sum += sl[j]; }
        #pragma unroll
        for (int m=0;m<24;++m){ sg[m] = __expf(sg[m]-mx); sum += sg[m]; }
        float inv = __builtin_amdgcn_rcpf(sum);
        // PL row (stride 32 sh, swizzled granules): local probs logical cols 4*lsq.., rest zero
        unsigned int lo = pack2bf(sl[0]*inv, sl[1]*inv);
        unsigned int hi = pack2bf(sl[2]*inv, sl[3]*inv);
        uint4 z4 = make_uint4(0u,0u,0u,0u);
        uint4 p0 = make_uint4(lsq==0?lo:0u, lsq==0?hi:0u, lsq==1?lo:0u, lsq==1?hi:0u);
        uint4 p1 = make_uint4(lsq==2?lo:0u, lsq==2?hi:0u, lsq==3?lo:0u, lsq==3?hi:0u);
        uint4* plp = (uint4*)(Ssh + PL_SH + f*32);
        int swp = (f >> 1) & 3;
        plp[0^swp] = p0; plp[1^swp] = p1; plp[2^swp] = z4; plp[3^swp] = z4;
        // PG row (stride 48 sh, overlay YB/YGB): 24 bf16 + 8 zeros
        unsigned int gdw[12];
        #pragma unroll
        for (int m=0;m<12;++m) gdw[m] = pack2bf(sg[2*m]*inv, sg[2*m+1]*inv);
        uint4* pgp = (uint4*)(Ssh + PG_SH + f*48);
        pgp[0] = make_uint4(gdw[0],gdw[1],gdw[2],gdw[3]);
        pgp[1] = make_uint4(gdw[4],gdw[5],gdw[6],gdw[7]);
        pgp[2] = make_uint4(gdw[8],gdw[9],gdw[10],gdw[11]);
        pgp[3] = z4;
    }
    __syncthreads();

    // ---- S6: o^T -> OB (stride 64 swizzled; overlays SC) ----
    {
        bfrag8 Avl = *(const bfrag8*)(Ssh + VLBT_SH + (16*w + n)*32 + ((q2^svl)<<3));
        #pragma unroll
        for (int nt=0; nt<6; ++nt){
            bfrag8 Avb = *(const bfrag8*)(Ssh + VBT_SH + (16*w + n)*96 + (((2*nt + q2)^svl)<<3));
            bfrag8 Bpl = *(const bfrag8*)(Ssh + PL_SH + (nt*16 + n)*32 + ((q2^svl)<<3));
            bfrag8 Bpg = *(const bfrag8*)(Ssh + PG_SH + (nt*16 + n)*48 + q2*8);
            facc4 acc = {0.f,0.f,0.f,0.f};
            acc = MFMA16(Avb, Bpl, acc, 0, 0, 0);
            acc = MFMA16(Avl, Bpg, acc, 0, 0, 0);
            uint2 pk = make_uint2(pack2bf(acc[0],acc[1]), pack2bf(acc[2],acc[3]));
            int go = 2*w + (q2>>1);
            *(uint2*)(Ssh + OB_SH + (nt*16 + n)*64 + ((go^swo)<<3) + ((q2&1)<<2)) = pk;
        }
    }
    __syncthreads();

    // ---- S7: out-proj + residual into XR ----
    for (int mt = w; mt < 6; mt += 4){
        bfrag8 A0 = *(const bfrag8*)(Ssh + OB_SH + (mt*16 + n)*64 + ((q2^swo)<<3));
        bfrag8 A1 = *(const bfrag8*)(Ssh + OB_SH + (mt*16 + n)*64 + (((4+q2)^swo)<<3));
        facc4 acc = {bor, bor, bor, bor};
        acc = MFMA16(A0, Bo0, acc, 0, 0, 0);
        acc = MFMA16(A1, Bo1, acc, 0, 0, 0);
        #pragma unroll
        for (int r=0;r<4;++r)
            S[XR_FL + (mt*16 + q2*4 + r)*16 + n] += acc[r];
    }
    __syncthreads();

    // ---- S8: MLP ----
    ln_stats16(S, tid);
    {
        float4* XR4 = (float4*)(S + XR_FL);
        for (int i4 = tid; i4 < 384; i4 += 256){
            int f = i4 >> 2, c4 = i4 & 3;
            float4 v = XR4[i4];
            float4 m4 = *(float4*)(S + MEA_FL + 4*c4);
            float4 r4 = *(float4*)(S + RST_FL + 4*c4);
            float gg = ln_m_g[f], b2 = ln_m_b[f];
            float y0 = (v.x - m4.x)*r4.x*gg + b2;
            float y1 = (v.y - m4.y)*r4.y*gg + b2;
            float y2 = (v.z - m4.z)*r4.z*gg + b2;
            float y3 = (v.w - m4.w)*r4.w*gg + b2;
            uint2 pk = make_uint2(pack2bf(y0,y1), pack2bf(y2,y3));
            *(uint2*)(Ssh + YB_SH + f*24 + c4*4) = pk;
        }
    }
    __syncthreads();
    for (int mt = w; mt < 6; mt += 4){
        bfrag8 A = ZF;
        if (q2 < 2) A = *(const bfrag8*)(Ssh + YB_SH + (mt*16 + n)*24 + q2*8);
        facc4 acc = {bm1r, bm1r, bm1r, bm1r};
        acc = MFMA16(A, Bm1, acc, 0, 0, 0);
        #pragma unroll
        for (int r=0;r<4;++r)
            Ssh[YGB_SH + (mt*16 + q2*4 + r)*24 + n] = (short)f2bf(gelu_erf(acc[r]));
    }
    __syncthreads();
    for (int mt = w; mt < 6; mt += 4){
        bfrag8 A = ZF;
        if (q2 < 2) A = *(const bfrag8*)(Ssh + YGB_SH + (mt*16 + n)*24 + q2*8);
        facc4 acc = {bm2r, bm2r, bm2r, bm2r};
        acc = MFMA16(A, Bm2, acc, 0, 0, 0);
        #pragma unroll
        for (int r=0;r<4;++r)
            S[XR_FL + (mt*16 + q2*4 + r)*16 + n] += acc[r];
    }
    __syncthreads();

    // ---- S9: conv_out + outer residual ----
    ln_stats16(S, tid);
    if (tid < 192){
        int ch = tid >= 96, f = tid - 96*ch;
        float gg = ln_o_g[f], b2 = ln_o_b[f];
        float acc = b_out[ch];
        float4* XR4 = (float4*)(S + XR_FL);
        #pragma unroll
        for (int c4=0;c4<4;++c4){
            float4 x4 = XR4[f*4 + c4];
            float4 m4 = *(float4*)(S + MEA_FL + 4*c4);
            float4 r4 = *(float4*)(S + RST_FL + 4*c4);
            float4 w4 = *(const float4*)(w_out + ch*16 + 4*c4);
            float4 tm;
            tm.x = (x4.x - m4.x)*r4.x*gg + b2;
            tm.y = (x4.y - m4.y)*r4.y*gg + b2;
            tm.z = (x4.z - m4.z)*r4.z*gg + b2;
            tm.w = (x4.w - m4.w)*r4.w*gg + b2;
            acc += dot4(w4, tm);
        }
        size_t oidx = ((size_t)(b*2+ch)*T_ + t)*F_ + f;
        out[oidx] = input[oidx] + tanhf(acc);
    }
}

extern "C" void kernel_launch(void* const* d_in, const int* in_sizes, int n_in,
                              void* d_out, int out_size, void* d_ws, size_t ws_size,
                              hipStream_t stream)
{
    const float* input   = (const float*)d_in[0];
    const float* ln_in_g = (const float*)d_in[1];
    const float* ln_in_b = (const float*)d_in[2];
    const float* w_in    = (const float*)d_in[3];
    const float* b_in    = (const float*)d_in[4];
    const float* gru_wx  = (const float*)d_in[5];
    const float* gru_wh  = (const float*)d_in[6];
    const float* ln_att_g= (const float*)d_in[7];
    const float* ln_att_b= (const float*)d_in[8];
    const float* wq = (const float*)d_in[9];
    const float* bq = (const float*)d_in[10];
    const float* wk = (const float*)d_in[11];
    const float* bk = (const float*)d_in[12];
    const float* wv = (const float*)d_in[13];
    const float* bv = (const float*)d_in[14];
    const float* wo = (const float*)d_in[15];
    const float* bo = (const float*)d_in[16];
    const float* ln_m_g = (const float*)d_in[17];
    const float* ln_m_b = (const float*)d_in[18];
    const float* w_m1 = (const float*)d_in[19];
    const float* b_m1 = (const float*)d_in[20];
    const float* w_m2 = (const float*)d_in[21];
    const float* b_m2 = (const float*)d_in[22];
    const float* ln_out_g = (const float*)d_in[23];
    const float* ln_out_b = (const float*)d_in[24];
    const float* w_out = (const float*)d_in[25];
    const float* b_out = (const float*)d_in[26];
    float* out = (float*)d_out;

    const size_t NX = (size_t)B_*T_*F_*C_;          // 12,288,000
    float* x   = (float*)d_ws;                      // [B,T,F,C]
    float* hs  = x + NX;                            // [B,T,F,C]
    float* uvw = x + 2*NX;                          // 33 floats (padded to 64)
    short* wv_bf  = (short*)(x + 2*NX + 64);        // 16B-aligned
    short* wo_bf  = wv_bf + 1024;
    short* wm1_bf = wo_bf + 1024;
    short* wm2_bf = wm1_bf + 256;
    short* gtb    = wm2_bf + 256;

    k_prep<<<1, 256, 0, stream>>>(wq, bq, wk, bk, wv, wo, w_m1, w_m2,
                                  gtb, uvw, wv_bf, wo_bf, wm1_bf, wm2_bf);
    k_conv_in<<<B_*T_, 128, 0, stream>>>(input, ln_in_g, ln_in_b, w_in, b_in, x);
    k_gru<<<192, 192, 0, stream>>>(x, gru_wx, gru_wh, hs, out);
    k_tail<<<B_*T_, 256, 0, stream>>>(x, hs, input, ln_att_g, ln_att_b,
        gtb, uvw, wv_bf, bv, wo_bf, bo, ln_m_g, ln_m_b, wm1_bf, b_m1, wm2_bf, b_m2,
        ln_out_g, ln_out_b, w_out, b_out, out);
}

// Round 7
// 419.131 us; speedup vs baseline: 1.1386x; 1.0173x over previous
//
#include <hip/hip_runtime.h>
#include <math.h>

#define B_ 8
#define T_ 1000
#define F_ 96
#define C_ 16
#define D_ 64
#define EPS_ 1e-5f
#define CH_ 40

typedef short bfrag8 __attribute__((ext_vector_type(8)));
typedef float facc4 __attribute__((ext_vector_type(4)));
typedef float f2v __attribute__((ext_vector_type(2)));
#define MFMA16 __builtin_amdgcn_mfma_f32_16x16x32_bf16

__device__ __forceinline__ float gelu_erf(float v){
    return 0.5f*v*(1.0f+erff(v*0.70710678118654752440f));
}
__device__ __forceinline__ float dot4(float4 a, float4 b){
    return a.x*b.x + a.y*b.y + a.z*b.z + a.w*b.w;
}
__device__ __forceinline__ float ex2(float x){   // 2^x, bare v_exp_f32
    float r; asm("v_exp_f32 %0, %1" : "=v"(r) : "v"(x)); return r;
}
__device__ __forceinline__ float ex2n(float x){  // 2^(-x)
    float r; asm("v_exp_f32 %0, -%1" : "=v"(r) : "v"(x)); return r;
}
__device__ __forceinline__ unsigned short f2bf(float x){
    unsigned int u = __float_as_uint(x);
    return (unsigned short)((u + 0x7fffu + ((u>>16)&1u)) >> 16);
}
__device__ __forceinline__ float bf2f(unsigned short s){
    return __uint_as_float(((unsigned int)s)<<16);
}
__device__ __forceinline__ unsigned int pack2bf(float a, float b){
    return (unsigned int)f2bf(a) | ((unsigned int)f2bf(b)<<16);
}

// ---------------- Kernel P: weight-only precompute (1 block) ----------------
__global__ __launch_bounds__(256) void k_prep(
    const float* __restrict__ wq, const float* __restrict__ bq,
    const float* __restrict__ wk, const float* __restrict__ bk,
    const float* __restrict__ wv, const float* __restrict__ wo,
    const float* __restrict__ wm1, const float* __restrict__ wm2,
    short* __restrict__ gtb, float* __restrict__ uvw,
    short* __restrict__ wv_bf, short* __restrict__ wo_bf,
    short* __restrict__ wm1_bf, short* __restrict__ wm2_bf)
{
    int tid = threadIdx.x;
    int c1 = tid & 15, c2 = tid >> 4;
    float acc = 0.f;
    #pragma unroll 8
    for (int d=0; d<64; ++d)
        acc += wq[d*16 + c1] * wk[d*16 + c2];
    gtb[c2*16 + c1] = (short)f2bf(0.125f * acc);
    if (tid < 16){
        float a = 0.f;
        for (int d=0; d<64; ++d) a += wq[d*16 + tid] * bk[d];
        uvw[tid] = 0.125f * a;
    } else if (tid < 32){
        int cc = tid - 16;
        float a = 0.f;
        for (int d=0; d<64; ++d) a += bq[d] * wk[d*16 + cc];
        uvw[16 + cc] = 0.125f * a;
    } else if (tid == 32){
        float a = 0.f;
        for (int d=0; d<64; ++d) a += bq[d] * bk[d];
        uvw[32] = 0.125f * a;
    }
    for (int i = tid; i < 1024; i += 256){
        wv_bf[i] = (short)f2bf(wv[i]);
        wo_bf[i] = (short)f2bf(wo[i]);
    }
    if (tid < 256){
        wm1_bf[tid] = (short)f2bf(wm1[tid]);
        wm2_bf[tid] = (short)f2bf(wm2[tid]);
    }
}

// ---------------- Kernel A: conv_in -> x [B,T,F,C] ----------------
__global__ __launch_bounds__(128) void k_conv_in(
    const float* __restrict__ in, const float* __restrict__ g, const float* __restrict__ bb,
    const float* __restrict__ w_in, const float* __restrict__ b_in,
    float* __restrict__ x)
{
    int bt = blockIdx.x; int b = bt / T_; int t = bt % T_;
    int tid = threadIdx.x;
    __shared__ float r0[128], r1[128], r2[128], r3[128];
    float i0=0.f, i1=0.f;
    size_t base0 = ((size_t)(b*2+0)*T_ + t)*F_;
    size_t base1 = ((size_t)(b*2+1)*T_ + t)*F_;
    if (tid < F_){ i0 = in[base0+tid]; i1 = in[base1+tid]; }
    r0[tid]=i0; r1[tid]=i0*i0; r2[tid]=i1; r3[tid]=i1*i1;
    __syncthreads();
    for (int s=64; s>0; s>>=1){
        if (tid < s){ r0[tid]+=r0[tid+s]; r1[tid]+=r1[tid+s]; r2[tid]+=r2[tid+s]; r3[tid]+=r3[tid+s]; }
        __syncthreads();
    }
    float m0 = r0[0]*(1.f/F_), m1 = r2[0]*(1.f/F_);
    float ri0 = rsqrtf(r1[0]*(1.f/F_) - m0*m0 + EPS_);
    float ri1 = rsqrtf(r3[0]*(1.f/F_) - m1*m1 + EPS_);
    if (tid < F_){
        float gg = g[tid], b0 = bb[tid];
        float y0 = (i0-m0)*ri0*gg + b0;
        float y1 = (i1-m1)*ri1*gg + b0;
        float xv[16];
        #pragma unroll
        for (int c=0;c<C_;++c){
            xv[c] = gelu_erf(w_in[c*2+0]*y0 + w_in[c*2+1]*y1 + b_in[c]);
        }
        float4* xp = (float4*)(x + (((size_t)b*T_+t)*F_ + tid)*C_);
        xp[0] = make_float4(xv[0],xv[1],xv[2],xv[3]);
        xp[1] = make_float4(xv[4],xv[5],xv[6],xv[7]);
        xp[2] = make_float4(xv[8],xv[9],xv[10],xv[11]);
        xp[3] = make_float4(xv[12],xv[13],xv[14],xv[15]);
    }
}

// ---------------- Kernel B: ConvGRU — 1 consumer + 3 producers, setprio'd consumer ----------------
#define DPPF(src, ctrl) __int_as_float(__builtin_amdgcn_update_dpp(0, __float_as_int(src), (ctrl), 0xF, 0xF, false))
#define L2E_ 1.44269504088896340736f

__global__ __launch_bounds__(256, 1) void k_gru(
    const float* __restrict__ x, const float* __restrict__ wx, const float* __restrict__ wh,
    float* __restrict__ hs, float* __restrict__ d_out)
{
    int blk = blockIdx.x;
    int b = blk / 24, f0 = (blk % 24) * 4;
    int tid = threadIdx.x;
    int wave = tid >> 6, lane = tid & 63;
    int c = lane & 15, ch = lane >> 4;
    int f = f0 + ch;

    __shared__ float GG[2][(CH_+1)*192];

    if (wave != 0){
        // -------- producers: waves 1..3, timestep split 14/14/12 of the 40-chunk --------
        float4 Wxz[4], Wxr[4], Wxn[4];
        #pragma unroll
        for (int q=0;q<4;++q){
            float4 az = *(const float4*)(wx + ( 0+c)*16 + 4*q);
            float4 ar = *(const float4*)(wx + (16+c)*16 + 4*q);
            float4 an = *(const float4*)(wx + (32+c)*16 + 4*q);
            Wxz[q] = make_float4(az.x*L2E_, az.y*L2E_, az.z*L2E_, az.w*L2E_);
            Wxr[q] = make_float4(ar.x*L2E_, ar.y*L2E_, ar.z*L2E_, ar.w*L2E_);
            Wxn[q] = make_float4(an.x*2.f*L2E_, an.y*2.f*L2E_, an.z*2.f*L2E_, an.w*2.f*L2E_);
        }
        const float* gb0 = x + (size_t)b*T_*(F_*C_) + f*C_;
        const int tl0 = (wave-1)*14;
        const int tl1 = (tl0 + 14 < CH_) ? tl0 + 14 : CH_;
        #define PRODUCE(K, BF) { \
            _Pragma("unroll 2") \
            for (int tl=tl0; tl<tl1; ++tl){ \
                const float* xp2 = gb0 + (size_t)((K)*CH_ + tl)*(F_*C_); \
                float4 x0 = *(const float4*)(xp2 + 0); \
                float4 x1 = *(const float4*)(xp2 + 4); \
                float4 x2 = *(const float4*)(xp2 + 8); \
                float4 x3 = *(const float4*)(xp2 + 12); \
                float zx = dot4(Wxz[0],x0)+dot4(Wxz[1],x1)+dot4(Wxz[2],x2)+dot4(Wxz[3],x3); \
                float rx = dot4(Wxr[0],x0)+dot4(Wxr[1],x1)+dot4(Wxr[2],x2)+dot4(Wxr[3],x3); \
                float nx = dot4(Wxn[0],x0)+dot4(Wxn[1],x1)+dot4(Wxn[2],x2)+dot4(Wxn[3],x3); \
                float* gq = &GG[BF][tl*192 + lane]; \
                gq[0] = zx; gq[64] = rx; gq[128] = nx; \
            } }
        PRODUCE(0, 0);
        __syncthreads();
        for (int k=0; k<T_/CH_; ++k){
            if (k+1 < T_/CH_){
                if ((k+1)&1){ PRODUCE(k+1, 1); } else { PRODUCE(k+1, 0); }
            }
            __syncthreads();
        }
        #undef PRODUCE
    } else {
        // -------- consumer: wave 0, serial recurrence, high priority --------
        __builtin_amdgcn_s_setprio(1);
        const int pm0[8] = {0,2,7,5,15,13,8,10};
        const int pm1[8] = {1,3,6,4,14,12,9,11};
        f2v Wz[8], Wr[8], Wn[8];
        #pragma unroll
        for (int j=0;j<8;++j){
            int ka = c ^ pm0[j], kb = c ^ pm1[j];
            Wz[j].x = L2E_*wh[( 0+c)*16 + ka];      Wz[j].y = L2E_*wh[( 0+c)*16 + kb];
            Wr[j].x = L2E_*wh[(16+c)*16 + ka];      Wr[j].y = L2E_*wh[(16+c)*16 + kb];
            Wn[j].x = 2.f*L2E_*wh[(32+c)*16 + ka];  Wn[j].y = 2.f*L2E_*wh[(32+c)*16 + kb];
        }
        float hc = 0.f;
        size_t hsb = (size_t)b*T_*(F_*C_) + f0*C_ + lane;
        __syncthreads();
        for (int k=0; k<T_/CH_; ++k){
            const float* gp = GG[k&1];
            float gzv = gp[lane], grv = gp[64+lane], gnv = gp[128+lane];
            #pragma unroll 8
            for (int tl=0; tl<CH_; ++tl){
                const float* np = gp + (tl+1)*192 + lane;
                float gzn = np[0], grn = np[64], gnn = np[128];
                f2v A0, P2, P7, P5, PF, PD, P8, PA;
                A0.x = hc;              A0.y = DPPF(hc, 0xB1);
                P2.x = DPPF(A0.x,0x4E); P2.y = DPPF(A0.y,0x4E);
                P7.x = DPPF(A0.x,0x141);P7.y = DPPF(A0.y,0x141);
                P5.x = DPPF(P7.x,0x4E); P5.y = DPPF(P7.y,0x4E);
                PF.x = DPPF(A0.x,0x140);PF.y = DPPF(A0.y,0x140);
                PD.x = DPPF(PF.x,0x4E); PD.y = DPPF(PF.y,0x4E);
                P8.x = DPPF(PF.x,0x141);P8.y = DPPF(PF.y,0x141);
                PA.x = DPPF(P8.x,0x4E); PA.y = DPPF(P8.y,0x4E);
                f2v sz = Wz[0]*A0, sr = Wr[0]*A0, sn = Wn[0]*A0;
                sz = __builtin_elementwise_fma(Wz[1],P2,sz);
                sr = __builtin_elementwise_fma(Wr[1],P2,sr);
                sn = __builtin_elementwise_fma(Wn[1],P2,sn);
                sz = __builtin_elementwise_fma(Wz[2],P7,sz);
                sr = __builtin_elementwise_fma(Wr[2],P7,sr);
                sn = __builtin_elementwise_fma(Wn[2],P7,sn);
                sz = __builtin_elementwise_fma(Wz[3],P5,sz);
                sr = __builtin_elementwise_fma(Wr[3],P5,sr);
                sn = __builtin_elementwise_fma(Wn[3],P5,sn);
                sz = __builtin_elementwise_fma(Wz[4],PF,sz);
                sr = __builtin_elementwise_fma(Wr[4],PF,sr);
                sn = __builtin_elementwise_fma(Wn[4],PF,sn);
                sz = __builtin_elementwise_fma(Wz[5],PD,sz);
                sr = __builtin_elementwise_fma(Wr[5],PD,sr);
                sn = __builtin_elementwise_fma(Wn[5],PD,sn);
                sz = __builtin_elementwise_fma(Wz[6],P8,sz);
                sr = __builtin_elementwise_fma(Wr[6],P8,sr);
                sn = __builtin_elementwise_fma(Wn[6],P8,sn);
                sz = __builtin_elementwise_fma(Wz[7],PA,sz);
                sr = __builtin_elementwise_fma(Wr[7],PA,sr);
                sn = __builtin_elementwise_fma(Wn[7],PA,sn);
                float z = __builtin_amdgcn_rcpf(1.f + ex2n((gzv + sz.x) + sz.y));
                float r = __builtin_amdgcn_rcpf(1.f + ex2n((grv + sr.x) + sr.y));
                float u = __builtin_amdgcn_rcpf(1.f + ex2(fmaf(r, sn.x + sn.y, gnv)));
                float n = fmaf(-2.f, u, 1.f);
                hc = n + z*(hc - n);
                hs[hsb + (size_t)(k*CH_ + tl)*(F_*C_)] = hc;
                gzv = gzn; grv = grn; gnv = gnn;
            }
            __syncthreads();
        }
        d_out[(size_t)B_*2*T_*F_ + ((size_t)b*C_ + c)*F_ + f] = hc;
    }
}

// ---------------- Kernel C: fused attention + MLP + conv_out (MFMA bf16) ----------------
// LDS map (float offsets; _SH = short = 2x). TOTF 13144 fl = 52.6 KB -> 3 blocks/CU.
// Swizzles (16B granules): OB g^=row&7 ; VBT/VLBT/PL g^=(row>>1)&3.
#define XR_FL   0        // [96][16] fp32 residual, in place (0..1536)
#define YB_SH   3072     // [96][24]sh bf16 ynorm / ynorm2          (fl 1536..2688)
#define YGB_SH  5376     // [96][24]sh bf16 y*G / Y1                (fl 2688..3840)
#define PG_SH   3072     // [96][48]sh long probs (overlay YB+YGB, S5-S6)
#define YMB_SH  7680     // [32][24]sh segment means                (fl 3840..4224)
#define E_FL    4224     // 96
#define GL_FL   4320     // 96
#define GM_FL   4416     // 24
#define VBT_SH  8880     // [64][96]sh v^T[d][f], swizzled          (fl 4440..7512)
#define VLBT_SH 15024    // [64][32]sh v_long^T[d][m], swizzled     (fl 7512..8536)
// ---- pool (fl 8536..13144), time-disjoint overlays:
#define SC_FL   8536     // [96][29] fp32 scores (S4-S5)
#define OB_SH   17072    // [96][64]sh o[f][d], swizzled (S6-S7)    (fl 8536..11608)
#define PL_SH   23216    // [96][32]sh local probs, swizzled (S5-S6)(fl 11608..13144)
#define GTB_SH  17072    // [16][24]sh G^T (S0-S3)                  (fl 8536..8728)
#define UU_FL   8728     // 16  (S0-S3)
#define VV_FL   8744     // 16  (S0-S3)
#define W0_FL   8760     // 1   (S0-S3)
#define OSC_FL  8776     // 512 LN scratch (S1b/S8/S9)
#define MEA_FL  9288     // 16
#define RST_FL  9304     // 16
#define TOTF    13144

__device__ __forceinline__ void ln_stats16(float* S, int tid){
    int c = tid & 15, g = tid >> 4;
    float s=0.f, q=0.f;
    #pragma unroll
    for (int i=0;i<6;++i){
        float v = S[XR_FL + (g*6+i)*16 + c];
        s += v; q += v*v;
    }
    S[OSC_FL + g*16 + c] = s;
    S[OSC_FL + 256 + g*16 + c] = q;
    __syncthreads();
    if (tid < 16){
        float Sm=0.f, Q=0.f;
        #pragma unroll
        for (int g2=0; g2<16; ++g2){
            Sm += S[OSC_FL + g2*16 + tid];
            Q  += S[OSC_FL + 256 + g2*16 + tid];
        }
        float m = Sm*(1.f/96.f);
        S[MEA_FL+tid] = m;
        S[RST_FL+tid] = rsqrtf(Q*(1.f/96.f) - m*m + EPS_);
    }
    __syncthreads();
}

__global__ __launch_bounds__(256) void k_tail(
    const float* __restrict__ x, const float* __restrict__ hs, const float* __restrict__ input,
    const float* __restrict__ ln_att_g, const float* __restrict__ ln_att_b,
    const short* __restrict__ gtb, const float* __restrict__ uvw,
    const short* __restrict__ wv_bf, const float* __restrict__ bv,
    const short* __restrict__ wo_bf, const float* __restrict__ bo,
    const float* __restrict__ ln_m_g, const float* __restrict__ ln_m_b,
    const short* __restrict__ wm1_bf, const float* __restrict__ bm1,
    const short* __restrict__ wm2_bf, const float* __restrict__ bm2,
    const float* __restrict__ ln_o_g, const float* __restrict__ ln_o_b,
    const float* __restrict__ w_out, const float* __restrict__ b_out,
    float* __restrict__ out)
{
    int bt = blockIdx.x; int b = bt / T_; int t = bt % T_;
    int tid = threadIdx.x;
    int w = tid >> 6, lane = tid & 63;
    int n = lane & 15, q2 = lane >> 4;
    __shared__ float S[TOTF];
    short* Ssh = (short*)S;
    const bfrag8 ZF = {0,0,0,0,0,0,0,0};
    const int svl = (n >> 1) & 3;   // swizzle key for VBT/VLBT/PL
    const int swo = n & 7;          // swizzle key for OB

    size_t xbase = ((size_t)b*T_ + t)*(size_t)(F_*C_);

    // ---- S0: loads ----
    {
        const float4* xg = (const float4*)(x + xbase);
        const float4* hg = (const float4*)(hs + xbase);
        float4* XR4 = (float4*)(S + XR_FL);
        for (int i4 = tid; i4 < 384; i4 += 256){
            float4 a = xg[i4], h = hg[i4];
            XR4[i4] = make_float4(a.x+h.x, a.y+h.y, a.z+h.z, a.w+h.w);
        }
        if (tid < 64){
            int cc2 = tid >> 2, c1g = (tid & 3)*4;
            *(uint2*)(Ssh + GTB_SH + cc2*24 + c1g) = *(const uint2*)(gtb + cc2*16 + c1g);
        } else if (tid < 97){
            S[UU_FL + (tid - 64)] = uvw[tid - 64];   // UU(16)|VV(16)|W0(1)
        }
    }
    bfrag8 Bv = ZF, Bm1 = ZF, Bm2 = ZF;
    if (q2 < 2){
        Bv  = *(const bfrag8*)(wv_bf  + (16*w + n)*16 + q2*8);
        Bm1 = *(const bfrag8*)(wm1_bf + n*16 + q2*8);
        Bm2 = *(const bfrag8*)(wm2_bf + n*16 + q2*8);
    }
    bfrag8 Bo0 = *(const bfrag8*)(wo_bf + n*64 + q2*8);
    bfrag8 Bo1 = *(const bfrag8*)(wo_bf + n*64 + 32 + q2*8);
    float bvr  = bv[16*w + n];
    float bor  = bo[n];
    float bm1r = bm1[n];
    float bm2r = bm2[n];
    __syncthreads();

    // ---- S1b: attention LN stats ----
    ln_stats16(S, tid);

    // ---- S2: normalize -> YB ----
    {
        float4* XR4 = (float4*)(S + XR_FL);
        for (int i4 = tid; i4 < 384; i4 += 256){
            int f = i4 >> 2, c4 = i4 & 3;
            float4 v = XR4[i4];
            float4 m4 = *(float4*)(S + MEA_FL + 4*c4);
            float4 r4 = *(float4*)(S + RST_FL + 4*c4);
            float gg = ln_att_g[f], b2 = ln_att_b[f];
            float y0 = (v.x - m4.x)*r4.x*gg + b2;
            float y1 = (v.y - m4.y)*r4.y*gg + b2;
            float y2 = (v.z - m4.z)*r4.z*gg + b2;
            float y3 = (v.w - m4.w)*r4.w*gg + b2;
            uint2 pk = make_uint2(pack2bf(y0,y1), pack2bf(y2,y3));
            *(uint2*)(Ssh + YB_SH + f*24 + c4*4) = pk;
        }
    }
    __syncthreads();

    // ---- S2b: E/GL, segment means, zero YMB rows 24..31 ----
    if (tid < 96){
        int f = tid;
        float yv[16];
        uint4 u0 = *(const uint4*)(Ssh + YB_SH + f*24);
        uint4 u1 = *(const uint4*)(Ssh + YB_SH + f*24 + 8);
        unsigned int uu[8] = {u0.x,u0.y,u0.z,u0.w,u1.x,u1.y,u1.z,u1.w};
        #pragma unroll
        for (int j=0;j<8;++j){
            yv[2*j]   = bf2f((unsigned short)(uu[j] & 0xffff));
            yv[2*j+1] = bf2f((unsigned short)(uu[j] >> 16));
        }
        float de = 0.f, dg = 0.f;
        #pragma unroll
        for (int cc=0; cc<16; ++cc){
            de += yv[cc]*S[UU_FL+cc];
            dg += yv[cc]*S[VV_FL+cc];
        }
        S[E_FL + f]  = de + S[W0_FL];
        S[GL_FL + f] = dg;
    }
    for (int e = tid; e < 384; e += 256){
        int m = e >> 4, cc = e & 15;
        float sm = bf2f((unsigned short)Ssh[YB_SH + (4*m+0)*24 + cc])
                 + bf2f((unsigned short)Ssh[YB_SH + (4*m+1)*24 + cc])
                 + bf2f((unsigned short)Ssh[YB_SH + (4*m+2)*24 + cc])
                 + bf2f((unsigned short)Ssh[YB_SH + (4*m+3)*24 + cc]);
        Ssh[YMB_SH + m*24 + cc] = (short)f2bf(0.25f*sm);
    }
    if (tid < 128){
        int row = 24 + (tid >> 4), cc = tid & 15;
        Ssh[YMB_SH + row*24 + cc] = 0;
    }
    __syncthreads();

    // ---- S3: MFMA — v (VBT sw), v_long (VLBT sw), YG; GM ----
    {
        #pragma unroll
        for (int mt=0; mt<6; ++mt){
            bfrag8 A = ZF;
            if (q2 < 2) A = *(const bfrag8*)(Ssh + YB_SH + (mt*16 + n)*24 + q2*8);
            facc4 acc = {bvr, bvr, bvr, bvr};
            acc = MFMA16(A, Bv, acc, 0, 0, 0);
            uint2 pk = make_uint2(pack2bf(acc[0],acc[1]), pack2bf(acc[2],acc[3]));
            int g = 2*mt + (q2>>1);
            *(uint2*)(Ssh + VBT_SH + (16*w + n)*96 + ((g^svl)<<3) + ((q2&1)<<2)) = pk;
        }
        #pragma unroll
        for (int mt=0; mt<2; ++mt){
            bfrag8 A = ZF;
            if (q2 < 2) A = *(const bfrag8*)(Ssh + YMB_SH + (mt*16 + n)*24 + q2*8);
            facc4 acc = {bvr, bvr, bvr, bvr};
            acc = MFMA16(A, Bv, acc, 0, 0, 0);
            uint2 pk = make_uint2(pack2bf(acc[0],acc[1]), pack2bf(acc[2],acc[3]));
            int g = 2*mt + (q2>>1);
            *(uint2*)(Ssh + VLBT_SH + (16*w + n)*32 + ((g^svl)<<3) + ((q2&1)<<2)) = pk;
        }
        bfrag8 Bg = ZF;
        if (q2 < 2) Bg = *(const bfrag8*)(Ssh + GTB_SH + n*24 + q2*8);
        for (int mt = w; mt < 6; mt += 4){
            bfrag8 A = ZF;
            if (q2 < 2) A = *(const bfrag8*)(Ssh + YB_SH + (mt*16 + n)*24 + q2*8);
            facc4 acc = {0.f,0.f,0.f,0.f};
            acc = MFMA16(A, Bg, acc, 0, 0, 0);
            #pragma unroll
            for (int r=0;r<4;++r)
                Ssh[YGB_SH + (mt*16 + q2*4 + r)*24 + n] = (short)f2bf(acc[r]);
        }
        if (tid >= 224 && tid < 248){
            int m = tid - 224;
            float a2 = 0.f;
            #pragma unroll
            for (int cc=0; cc<16; ++cc)
                a2 += bf2f((unsigned short)Ssh[YMB_SH + m*24 + cc]) * S[VV_FL + cc];
            S[GM_FL + m] = a2;
        }
    }
    __syncthreads();

    // ---- S4: scores -> SC stride 29 (local compacted to cols 0..3) ----
    for (int j = w; j < 18; j += 4){
        int mt = j / 3, kind = j % 3;
        bfrag8 A = ZF;
        if (q2 < 2) A = *(const bfrag8*)(Ssh + YGB_SH + (mt*16 + n)*24 + q2*8);
        bfrag8 Bf = ZF;
        if (kind == 0){
            if (q2 < 2) Bf = *(const bfrag8*)(Ssh + YB_SH + (mt*16 + n)*24 + q2*8);
        } else {
            int nt = kind - 1;
            if (q2 < 2) Bf = *(const bfrag8*)(Ssh + YMB_SH + (nt*16 + n)*24 + q2*8);
        }
        facc4 acc = {0.f,0.f,0.f,0.f};
        acc = MFMA16(A, Bf, acc, 0, 0, 0);
        if (kind == 0){
            if ((n >> 2) == q2){
                #pragma unroll
                for (int r=0;r<4;++r)
                    S[SC_FL + (mt*16 + q2*4 + r)*29 + (n & 3)] = acc[r];
            }
        } else {
            int nt = kind - 1;
            if (!(nt == 1 && n >= 8)){
                #pragma unroll
                for (int r=0;r<4;++r)
                    S[SC_FL + (mt*16 + q2*4 + r)*29 + 4 + nt*16 + n] = acc[r];
            }
        }
    }
    __syncthreads();

    // ---- S5: softmax (threads 0..95) ----
    if (tid < 96){
        int f = tid;
        int lsq = (f >> 2) & 3;
        float e_ = S[E_FL + f];
        const float* row = S + SC_FL + f*29;
        float sl[4];
        #pragma unroll
        for (int j=0;j<4;++j)
            sl[j] = row[j] + e_ + S[GL_FL + (f & ~3) + j];
        float sg[24];
        #pragma unroll
        for (int m=0;m<24;++m)
            sg[m] = row[4 + m] + e_ + S[GM_FL + m];
        float mx = sl[0];
        #pragma unroll
        for (int j=1;j<4;++j) mx = fmaxf(mx, sl[j]);
        #pragma unroll
        for (int m=0;m<24;++m) mx = fmaxf(mx, sg[m]);
        float sum = 0.f;
        #pragma unroll
        for (int j=0;j<4;++j){ sl[j] = __expf(sl[j]-mx); sum += sl[j]; }
        #pragma unroll
        for (int m=0;m<24;++m){ sg[m] = __expf(sg[m]-mx); sum += sg[m]; }
        float inv = __builtin_amdgcn_rcpf(sum);
        // PL row (stride 32 sh, swizzled granules)
        unsigned int lo = pack2bf(sl[0]*inv, sl[1]*inv);
        unsigned int hi = pack2bf(sl[2]*inv, sl[3]*inv);
        uint4 z4 = make_uint4(0u,0u,0u,0u);
        uint4 p0 = make_uint4(lsq==0?lo:0u, lsq==0?hi:0u, lsq==1?lo:0u, lsq==1?hi:0u);
        uint4 p1 = make_uint4(lsq==2?lo:0u, lsq==2?hi:0u, lsq==3?lo:0u, lsq==3?hi:0u);
        uint4* plp = (uint4*)(Ssh + PL_SH + f*32);
        int swp = (f >> 1) & 3;
        plp[0^swp] = p0; plp[1^swp] = p1; plp[2^swp] = z4; plp[3^swp] = z4;
        // PG row (stride 48 sh, overlay YB/YGB): 24 bf16 + 8 zeros
        unsigned int gdw[12];
        #pragma unroll
        for (int m=0;m<12;++m) gdw[m] = pack2bf(sg[2*m]*inv, sg[2*m+1]*inv);
        uint4* pgp = (uint4*)(Ssh + PG_SH + f*48);
        pgp[0] = make_uint4(gdw[0],gdw[1],gdw[2],gdw[3]);
        pgp[1] = make_uint4(gdw[4],gdw[5],gdw[6],gdw[7]);
        pgp[2] = make_uint4(gdw[8],gdw[9],gdw[10],gdw[11]);
        pgp[3] = z4;
    }
    __syncthreads();

    // ---- S6: o^T -> OB (stride 64 swizzled; overlays SC) ----
    {
        bfrag8 Avl = *(const bfrag8*)(Ssh + VLBT_SH + (16*w + n)*32 + ((q2^svl)<<3));
        #pragma unroll
        for (int nt=0; nt<6; ++nt){
            bfrag8 Avb = *(const bfrag8*)(Ssh + VBT_SH + (16*w + n)*96 + (((2*nt + q2)^svl)<<3));
            bfrag8 Bpl = *(const bfrag8*)(Ssh + PL_SH + (nt*16 + n)*32 + ((q2^svl)<<3));
            bfrag8 Bpg = *(const bfrag8*)(Ssh + PG_SH + (nt*16 + n)*48 + q2*8);
            facc4 acc = {0.f,0.f,0.f,0.f};
            acc = MFMA16(Avb, Bpl, acc, 0, 0, 0);
            acc = MFMA16(Avl, Bpg, acc, 0, 0, 0);
            uint2 pk = make_uint2(pack2bf(acc[0],acc[1]), pack2bf(acc[2],acc[3]));
            int go = 2*w + (q2>>1);
            *(uint2*)(Ssh + OB_SH + (nt*16 + n)*64 + ((go^swo)<<3) + ((q2&1)<<2)) = pk;
        }
    }
    __syncthreads();

    // ---- S7: out-proj + residual into XR ----
    for (int mt = w; mt < 6; mt += 4){
        bfrag8 A0 = *(const bfrag8*)(Ssh + OB_SH + (mt*16 + n)*64 + ((q2^swo)<<3));
        bfrag8 A1 = *(const bfrag8*)(Ssh + OB_SH + (mt*16 + n)*64 + (((4+q2)^swo)<<3));
        facc4 acc = {bor, bor, bor, bor};
        acc = MFMA16(A0, Bo0, acc, 0, 0, 0);
        acc = MFMA16(A1, Bo1, acc, 0, 0, 0);
        #pragma unroll
        for (int r=0;r<4;++r)
            S[XR_FL + (mt*16 + q2*4 + r)*16 + n] += acc[r];
    }
    __syncthreads();

    // ---- S8: MLP ----
    ln_stats16(S, tid);
    {
        float4* XR4 = (float4*)(S + XR_FL);
        for (int i4 = tid; i4 < 384; i4 += 256){
            int f = i4 >> 2, c4 = i4 & 3;
            float4 v = XR4[i4];
            float4 m4 = *(float4*)(S + MEA_FL + 4*c4);
            float4 r4 = *(float4*)(S + RST_FL + 4*c4);
            float gg = ln_m_g[f], b2 = ln_m_b[f];
            float y0 = (v.x - m4.x)*r4.x*gg + b2;
            float y1 = (v.y - m4.y)*r4.y*gg + b2;
            float y2 = (v.z - m4.z)*r4.z*gg + b2;
            float y3 = (v.w - m4.w)*r4.w*gg + b2;
            uint2 pk = make_uint2(pack2bf(y0,y1), pack2bf(y2,y3));
            *(uint2*)(Ssh + YB_SH + f*24 + c4*4) = pk;
        }
    }
    __syncthreads();
    for (int mt = w; mt < 6; mt += 4){
        bfrag8 A = ZF;
        if (q2 < 2) A = *(const bfrag8*)(Ssh + YB_SH + (mt*16 + n)*24 + q2*8);
        facc4 acc = {bm1r, bm1r, bm1r, bm1r};
        acc = MFMA16(A, Bm1, acc, 0, 0, 0);
        #pragma unroll
        for (int r=0;r<4;++r)
            Ssh[YGB_SH + (mt*16 + q2*4 + r)*24 + n] = (short)f2bf(gelu_erf(acc[r]));
    }
    __syncthreads();
    for (int mt = w; mt < 6; mt += 4){
        bfrag8 A = ZF;
        if (q2 < 2) A = *(const bfrag8*)(Ssh + YGB_SH + (mt*16 + n)*24 + q2*8);
        facc4 acc = {bm2r, bm2r, bm2r, bm2r};
        acc = MFMA16(A, Bm2, acc, 0, 0, 0);
        #pragma unroll
        for (int r=0;r<4;++r)
            S[XR_FL + (mt*16 + q2*4 + r)*16 + n] += acc[r];
    }
    __syncthreads();

    // ---- S9: conv_out + outer residual ----
    ln_stats16(S, tid);
    if (tid < 192){
        int ch = tid >= 96, f = tid - 96*ch;
        float gg = ln_o_g[f], b2 = ln_o_b[f];
        float acc = b_out[ch];
        float4* XR4 = (float4*)(S + XR_FL);
        #pragma unroll
        for (int c4=0;c4<4;++c4){
            float4 x4 = XR4[f*4 + c4];
            float4 m4 = *(float4*)(S + MEA_FL + 4*c4);
            float4 r4 = *(float4*)(S + RST_FL + 4*c4);
            float4 w4 = *(const float4*)(w_out + ch*16 + 4*c4);
            float4 tm;
            tm.x = (x4.x - m4.x)*r4.x*gg + b2;
            tm.y = (x4.y - m4.y)*r4.y*gg + b2;
            tm.z = (x4.z - m4.z)*r4.z*gg + b2;
            tm.w = (x4.w - m4.w)*r4.w*gg + b2;
            acc += dot4(w4, tm);
        }
        size_t oidx = ((size_t)(b*2+ch)*T_ + t)*F_ + f;
        out[oidx] = input[oidx] + tanhf(acc);
    }
}

extern "C" void kernel_launch(void* const* d_in, const int* in_sizes, int n_in,
                              void* d_out, int out_size, void* d_ws, size_t ws_size,
                              hipStream_t stream)
{
    const float* input   = (const float*)d_in[0];
    const float* ln_in_g = (const float*)d_in[1];
    const float* ln_in_b = (const float*)d_in[2];
    const float* w_in    = (const float*)d_in[3];
    const float* b_in    = (const float*)d_in[4];
    const float* gru_wx  = (const float*)d_in[5];
    const float* gru_wh  = (const float*)d_in[6];
    const float* ln_att_g= (const float*)d_in[7];
    const float* ln_att_b= (const float*)d_in[8];
    const float* wq = (const float*)d_in[9];
    const float* bq = (const float*)d_in[10];
    const float* wk = (const float*)d_in[11];
    const float* bk = (const float*)d_in[12];
    const float* wv = (const float*)d_in[13];
    const float* bv = (const float*)d_in[14];
    const float* wo = (const float*)d_in[15];
    const float* bo = (const float*)d_in[16];
    const float* ln_m_g = (const float*)d_in[17];
    const float* ln_m_b = (const float*)d_in[18];
    const float* w_m1 = (const float*)d_in[19];
    const float* b_m1 = (const float*)d_in[20];
    const float* w_m2 = (const float*)d_in[21];
    const float* b_m2 = (const float*)d_in[22];
    const float* ln_out_g = (const float*)d_in[23];
    const float* ln_out_b = (const float*)d_in[24];
    const float* w_out = (const float*)d_in[25];
    const float* b_out = (const float*)d_in[26];
    float* out = (float*)d_out;

    const size_t NX = (size_t)B_*T_*F_*C_;          // 12,288,000
    float* x   = (float*)d_ws;                      // [B,T,F,C]
    float* hs  = x + NX;                            // [B,T,F,C]
    float* uvw = x + 2*NX;                          // 33 floats (padded to 64)
    short* wv_bf  = (short*)(x + 2*NX + 64);        // 16B-aligned
    short* wo_bf  = wv_bf + 1024;
    short* wm1_bf = wo_bf + 1024;
    short* wm2_bf = wm1_bf + 256;
    short* gtb    = wm2_bf + 256;

    k_prep<<<1, 256, 0, stream>>>(wq, bq, wk, bk, wv, wo, w_m1, w_m2,
                                  gtb, uvw, wv_bf, wo_bf, wm1_bf, wm2_bf);
    k_conv_in<<<B_*T_, 128, 0, stream>>>(input, ln_in_g, ln_in_b, w_in, b_in, x);
    k_gru<<<192, 256, 0, stream>>>(x, gru_wx, gru_wh, hs, out);
    k_tail<<<B_*T_, 256, 0, stream>>>(x, hs, input, ln_att_g, ln_att_b,
        gtb, uvw, wv_bf, bv, wo_bf, bo, ln_m_g, ln_m_b, wm1_bf, b_m1, wm2_bf, b_m2,
        ln_out_g, ln_out_b, w_out, b_out, out);
}